// Round 9
// baseline (800.013 us; speedup 1.0000x reference)
//
#include <hip/hip_runtime.h>
#include <math.h>

#define HW 1024
#define GRID 768
#define SMEM_BYTES 52608

typedef __attribute__((ext_vector_type(8))) short bf16x8;
typedef __attribute__((ext_vector_type(4))) float floatx4;

__device__ __forceinline__ unsigned short f2bf(float f) {
    unsigned u = __float_as_uint(f);
    u += 0x7FFF + ((u >> 16) & 1);
    return (unsigned short)(u >> 16);
}
__device__ __forceinline__ float bf2f(unsigned short u) {
    return __uint_as_float(((unsigned)u) << 16);
}
__device__ __forceinline__ float bflo(unsigned u) { return __uint_as_float(u << 16); }
__device__ __forceinline__ float bfhi(unsigned u) { return __uint_as_float(u & 0xffff0000u); }

// ---------------------------------------------------------------------------
// Bilinear sample, zero padding, absolute pixel coords (matches reference).
// ---------------------------------------------------------------------------
__device__ __forceinline__ float bilin32(const float* __restrict__ img, float px, float py) {
    float x0f = floorf(px), y0f = floorf(py);
    float wx = px - x0f, wy = py - y0f;
    bool vx0 = (x0f >= 0.f) && (x0f <= 31.f);
    bool vx1 = (x0f >= -1.f) && (x0f <= 30.f);
    bool vy0 = (y0f >= 0.f) && (y0f <= 31.f);
    bool vy1 = (y0f >= -1.f) && (y0f <= 30.f);
    int ix0 = (int)fminf(fmaxf(x0f, 0.f), 31.f);
    int iy0 = (int)fminf(fmaxf(y0f, 0.f), 31.f);
    int ix1 = (int)fminf(fmaxf(x0f + 1.f, 0.f), 31.f);
    int iy1 = (int)fminf(fmaxf(y0f + 1.f, 0.f), 31.f);
    float w00 = (1.f - wx) * (1.f - wy) * ((vx0 && vy0) ? 1.f : 0.f);
    float w01 = wx * (1.f - wy) * ((vx1 && vy0) ? 1.f : 0.f);
    float w10 = (1.f - wx) * wy * ((vx0 && vy1) ? 1.f : 0.f);
    float w11 = wx * wy * ((vx1 && vy1) ? 1.f : 0.f);
    return w00 * img[iy0 * 32 + ix0] + w01 * img[iy0 * 32 + ix1] +
           w10 * img[iy1 * 32 + ix0] + w11 * img[iy1 * 32 + ix1];
}

__device__ __forceinline__ float2 comp_flow(const float* __restrict__ fa,
                                            const float* __restrict__ fb, int pix) {
    int y = pix >> 5, x = pix & 31;
    float fx = fa[pix], fy = fa[HW + pix];
    float px = (float)x + fx, py = (float)y + fy;
    float2 r;
    r.x = fx + bilin32(fb, px, py);
    r.y = fy + bilin32(fb + HW, px, py);
    return r;
}

// ---------------------------------------------------------------------------
// Kernel argument block (small; all derived pointers computed on device).
// wp[i] = d_in[5+i]: vp0_w,b, vp1_w,b, so0_w,b, so1_w,b, so2_w,b, so3_w,b,
//                    aw0_w,b, aw1_w,b, aw2_w,b, aw3_w,b, op0_w,b, op1_w,b
// ---------------------------------------------------------------------------
struct MegaA {
    const float* x;
    const float* f1; const float* f2; const float* ff1; const float* ff2;
    const float* wp[24];
    float* out;
    char* ws;
    int* bar;
};

// ---------------------------------------------------------------------------
// Grid barrier: agent-scope atomics. __threadfence() on gfx950 emits the
// L2 writeback/invalidate needed for cross-XCD visibility.
// ---------------------------------------------------------------------------
__device__ __forceinline__ void grid_bar(int* bar, int phase) {
    __syncthreads();
    if (threadIdx.x == 0) {
        __threadfence();
        __hip_atomic_fetch_add(bar + phase * 16, 1, __ATOMIC_ACQ_REL, __HIP_MEMORY_SCOPE_AGENT);
        while (__hip_atomic_load(bar + phase * 16, __ATOMIC_RELAXED, __HIP_MEMORY_SCOPE_AGENT) < GRID)
            __builtin_amdgcn_s_sleep(8);
        __threadfence();
    }
    __syncthreads();
}

// ---------------------------------------------------------------------------
// Prep phase (vb 0..3775): xpad / build_extra / flows / borders / wxform.
// ---------------------------------------------------------------------------
__device__ __forceinline__ void prep_tile(const MegaA& A, float* fcn2, float* fn2c,
                                          unsigned short* x_pad, unsigned short* extra_pad,
                                          unsigned short* wgt, int b, char* smraw) {
    const int tid = threadIdx.x;
    const float* x = A.x;
    if (b < 192) {
        int idx = b * 256 + tid;
        int pix = idx / 48, c4 = idx - pix * 48;
        int y = pix >> 5, xx = pix & 31;
        int c0 = c4 * 4;
        ushort4 s;
        s.x = f2bf(x[(size_t)(c0 + 0) * HW + pix]);
        s.y = f2bf(x[(size_t)(c0 + 1) * HW + pix]);
        s.z = f2bf(x[(size_t)(c0 + 2) * HW + pix]);
        s.w = f2bf(x[(size_t)(c0 + 3) * HW + pix]);
        *(ushort4*)(&x_pad[(size_t)((y + 1) * 34 + xx + 1) * 192 + c0]) = s;
    } else if (b < 2112) {
        int idx = (b - 192) * 256 + tid;
        int ch = idx >> 10, pix = idx & 1023;
        int y = pix >> 5, xx = pix & 31;
        float v = 0.f;
        if (ch < 64) {
            v = x[(size_t)ch * HW + pix];
        } else if (ch < 448) {
            int grp = (ch - 64) >> 6;
            int c = (ch - 64) & 63;
            const float* src;
            float fx, fy;
            if (grp == 0)      { src = x + 64 * HW;  fx = A.f1[pix];  fy = A.f1[HW + pix]; }
            else if (grp == 1) { src = x + 128 * HW; float2 r = comp_flow(A.f1, A.f2, pix);  fx = r.x; fy = r.y; }
            else if (grp == 2) { src = x;            fx = A.ff1[pix]; fy = A.ff1[HW + pix]; }
            else if (grp == 3) { src = x + 128 * HW; fx = A.f2[pix];  fy = A.f2[HW + pix]; }
            else if (grp == 4) { src = x + 64 * HW;  fx = A.ff2[pix]; fy = A.ff2[HW + pix]; }
            else               { src = x;            float2 r = comp_flow(A.ff2, A.ff1, pix); fx = r.x; fy = r.y; }
            v = bilin32(src + c * HW, (float)xx + fx, (float)y + fy);
        } else if (ch < 460) {
            int fc = ch - 448;
            int which = fc >> 1, comp = fc & 1;
            if (which == 0)      v = A.f1[comp * HW + pix];
            else if (which == 1) { float2 r = comp_flow(A.f1, A.f2, pix);  v = comp ? r.y : r.x; }
            else if (which == 2) v = A.ff1[comp * HW + pix];
            else if (which == 3) v = A.f2[comp * HW + pix];
            else if (which == 4) v = A.ff2[comp * HW + pix];
            else                 { float2 r = comp_flow(A.ff2, A.ff1, pix); v = comp ? r.y : r.x; }
        }
        extra_pad[(size_t)((y + 1) * 34 + xx + 1) * 480 + ch] = f2bf(v);
    } else if (b < 2128) {
        int idx = (b - 2112) * 256 + tid;
        if (idx < 1024) {
            float2 r = comp_flow(A.f1, A.f2, idx);
            fcn2[idx] = r.x; fcn2[HW + idx] = r.y;
        } else if (idx < 2048) {
            int pix = idx - 1024;
            float2 r = comp_flow(A.ff2, A.ff1, pix);
            fn2c[pix] = r.x; fn2c[HW + pix] = r.y;
        }
    } else if (b < 2144) {
        const int chans[9] = {192, 192, 480, 64, 64, 64, 64, 192, 192};
        size_t offs[9]; size_t a = 0;
        for (int i = 0; i < 9; ++i) { offs[i] = a; a += (size_t)1156 * chans[i]; }
        int bb = b - 2128;
        for (int item = bb; item < 9 * 132; item += 16) {
            int buf = item / 132, i = item - buf * 132;
            int py, px;
            if (i < 34) { py = 0; px = i; }
            else if (i < 68) { py = 33; px = i - 34; }
            else { int j = i - 68; py = 1 + (j >> 1); px = (j & 1) ? 33 : 0; }
            int C = chans[buf];
            unsigned short* p = x_pad + offs[buf] + (size_t)(py * 34 + px) * C;
            for (int c = tid; c < C; c += 256) p[c] = 0;
        }
    } else {
        float* wlds = (float*)smraw;
        int blk = b - 2144;                      // < 1632
        const int wcout[12] = {192,192,64,64,64,64,64,64,1728,7776,192,192};
        const int wcin[12]  = {192,192,460,460,64,64,64,64,64,64,192,192};
        const int wnCb[12]  = {6,6,15,15,2,2,2,2,2,2,6,6};
        const int wbase[12] = {0,648,1296,1836,2376,2448,2520,2592,2664,4608,13392,14040};
        const int wbeg[12]  = {0,72,144,204,264,272,280,288,296,512,1488,1560};
        int di = 0;
        while (di < 11 && blk >= wbeg[di + 1]) ++di;
        const float* wsrc;
        switch (di) {
            case 0: wsrc = A.wp[0]; break;  case 1: wsrc = A.wp[2]; break;
            case 2: wsrc = A.wp[4]; break;  case 3: wsrc = A.wp[12]; break;
            case 4: wsrc = A.wp[6]; break;  case 5: wsrc = A.wp[14]; break;
            case 6: wsrc = A.wp[8]; break;  case 7: wsrc = A.wp[16]; break;
            case 8: wsrc = A.wp[10]; break; case 9: wsrc = A.wp[18]; break;
            case 10: wsrc = A.wp[20]; break; default: wsrc = A.wp[22]; break;
        }
        int cout = wcout[di], Cin = wcin[di], nCb = wnCb[di];
        int local = blk - wbeg[di];
        int co16 = local / nCb, cb = local - co16 * nCb;
        int cr0 = co16 * 16, ci0 = cb * 32;
        __syncthreads();
        for (int i = tid; i < 16 * 288; i += 256) {
            int cr = i / 288, o = i - cr * 288;
            int crg = cr0 + cr, ci = ci0 + o / 9;
            float v = (crg < cout && ci < Cin)
                ? wsrc[((size_t)crg * Cin + ci0) * 9 + o] : 0.f;
            wlds[i] = v;
        }
        __syncthreads();
        for (int e = tid; e < 9 * 512; e += 256) {
            int t = e >> 9, idx = e & 511;
            int j = idx & 7, lane = idx >> 3, q = lane >> 4, mm = lane & 15;
            wgt[((size_t)wbase[di] + ((size_t)co16 * 9 + t) * nCb + cb) * 512 + idx] =
                f2bf(wlds[mm * 288 + (q * 8 + j) * 9 + t]);
        }
    }
}

// ---------------------------------------------------------------------------
// MFMA 3x3 conv tile (register-prefetch double-buffered), as device function.
// ---------------------------------------------------------------------------
struct CDesc {
    const unsigned short* in;
    const unsigned short* wgt;
    const float* bias;
    void* out;
    const float* residual;
    int Cpad, nCb, Cout, mode, cmod, relu;
};

template<int PIXROWS, int COBLK>
__device__ __forceinline__ void conv_tile(const CDesc d, int bx, int by, char* smraw) {
    constexpr int TROWS = PIXROWS + 2;
    constexpr int TC = TROWS * 34 * 4;
    constexpr int ITRIPS = (TC + 255) / 256;
    constexpr int NTY = PIXROWS / 4;
    constexpr int NACC = NTY * 2;
    constexpr int MT = COBLK / 16;
    constexpr int WN = MT * 9 * 64;
    constexpr int WTRIPS = (WN + 255) / 256;
    unsigned short* blds = (unsigned short*)smraw;                       // TROWS*34*40
    unsigned short* wlds = (unsigned short*)(smraw + TROWS * 34 * 40 * 2); // MT*9*512

    const int tid = threadIdx.x;
    const int w = tid >> 6, lane = tid & 63;
    const int lq = lane >> 4, ln = lane & 15;
    const int co0 = bx * COBLK;
    const int y0 = by * PIXROWS;
    const unsigned short* __restrict__ in = d.in;
    const unsigned short* __restrict__ wg = d.wgt;
    const int Cpad = d.Cpad, nCb = d.nCb;

    floatx4 acc[MT][NACC];
#pragma unroll
    for (int mt = 0; mt < MT; ++mt)
#pragma unroll
        for (int nt = 0; nt < NACC; ++nt)
            acc[mt][nt] = (floatx4){0.f, 0.f, 0.f, 0.f};

    bf16x8 ireg[ITRIPS];
    bf16x8 wreg[WTRIPS];

    auto load_regs = [&](int cb) {
        const int ci0 = cb << 5;
#pragma unroll
        for (int k = 0; k < ITRIPS; ++k) {
            int i = tid + k * 256;
            if (i < TC) {
                int r = i / 136, rem = i - r * 136, c = rem >> 2, g = rem & 3;
                ireg[k] = *(const bf16x8*)(in + (size_t)((y0 + r) * 34 + c) * Cpad + ci0 + g * 8);
            }
        }
#pragma unroll
        for (int k = 0; k < WTRIPS; ++k) {
            int i = tid + k * 256;
            if (i < WN) {
                int chunk = i >> 6, l16 = i & 63;
                int mt = chunk / 9, t = chunk - mt * 9;
                wreg[k] = *(const bf16x8*)(wg + ((size_t)(((co0 >> 4) + mt) * 9 + t) * nCb + cb) * 512 + l16 * 8);
            }
        }
    };

    load_regs(0);

    for (int cb = 0; cb < nCb; ++cb) {
        __syncthreads();
#pragma unroll
        for (int k = 0; k < ITRIPS; ++k) {
            int i = tid + k * 256;
            if (i < TC) {
                int r = i / 136, rem = i - r * 136, c = rem >> 2, g = rem & 3;
                *(bf16x8*)(&blds[(r * 34 + c) * 40 + g * 8]) = ireg[k];
            }
        }
#pragma unroll
        for (int k = 0; k < WTRIPS; ++k) {
            int i = tid + k * 256;
            if (i < WN) {
                int chunk = i >> 6, l16 = i & 63;
                *(bf16x8*)(&wlds[chunk * 512 + l16 * 8]) = wreg[k];
            }
        }
        __syncthreads();
        if (cb + 1 < nCb) load_regs(cb + 1);
        for (int t = 0; t < 9; ++t) {
            const int dy = t / 3, dx = t - dy * 3;
            bf16x8 bfr[NACC];
#pragma unroll
            for (int ty = 0; ty < NTY; ++ty)
#pragma unroll
                for (int tx = 0; tx < 2; ++tx) {
                    int yy = w * NTY + ty + dy;
                    int xx = tx * 16 + ln + dx;
                    bfr[ty * 2 + tx] = *(const bf16x8*)(&blds[(yy * 34 + xx) * 40 + lq * 8]);
                }
#pragma unroll
            for (int mt = 0; mt < MT; ++mt) {
                bf16x8 afr = *(const bf16x8*)(&wlds[(mt * 9 + t) * 512 + lane * 8]);
#pragma unroll
                for (int nt = 0; nt < NACC; ++nt)
                    acc[mt][nt] = __builtin_amdgcn_mfma_f32_16x16x32_bf16(afr, bfr[nt], acc[mt][nt], 0, 0, 0);
            }
        }
    }

#pragma unroll
    for (int mt = 0; mt < MT; ++mt) {
        const int co = co0 + mt * 16 + lq * 4;
        if (co >= d.Cout) continue;
        float bv[4];
#pragma unroll
        for (int r = 0; r < 4; ++r) bv[r] = d.bias[co + r];
#pragma unroll
        for (int nt = 0; nt < NACC; ++nt) {
            const int ty = nt >> 1, tx = nt & 1;
            const int pix = by * (PIXROWS * 32) + (w * NTY + ty) * 32 + tx * 16 + ln;
            float v[4];
#pragma unroll
            for (int r = 0; r < 4; ++r) {
                float vv = acc[mt][nt][r] + bv[r];
                if (d.relu) vv = (vv >= 0.f) ? vv : 0.1f * vv;
                v[r] = vv;
            }
            if (d.mode == 0) {
                float* o = (float*)d.out;
#pragma unroll
                for (int r = 0; r < 4; ++r) {
                    float vv = v[r];
                    if (d.residual) vv += d.residual[(size_t)(co + r) * HW + pix];
                    o[(size_t)(co + r) * HW + pix] = vv;
                }
            } else if (d.mode == 1) {
                int fq = co / d.cmod, cc = co - fq * d.cmod;
                *(float4*)((float*)d.out + ((size_t)fq * HW + pix) * d.cmod + cc) =
                    make_float4(v[0], v[1], v[2], v[3]);
            } else if (d.mode == 2) {
                int fq = co / d.cmod, cc = co - fq * d.cmod;
                ushort4 s4;
                s4.x = f2bf(v[0]); s4.y = f2bf(v[1]); s4.z = f2bf(v[2]); s4.w = f2bf(v[3]);
                *(ushort4*)((unsigned short*)d.out + ((size_t)fq * HW + pix) * d.cmod + cc) = s4;
            } else {
                int yy = (pix >> 5) + 1, xx = (pix & 31) + 1;
                ushort4 s4;
                s4.x = f2bf(v[0]); s4.y = f2bf(v[1]); s4.z = f2bf(v[2]); s4.w = f2bf(v[3]);
                *(ushort4*)((unsigned short*)d.out + (size_t)(yy * 34 + xx) * d.cmod + co) = s4;
            }
        }
    }
}

// ---------------------------------------------------------------------------
// Deformable attention tile (LDS value + patch-convolution gathers).
// ---------------------------------------------------------------------------
__device__ __forceinline__ void attn_tile(
    const unsigned short* __restrict__ value_b, const float* __restrict__ so_t,
    const unsigned short* __restrict__ aw_t,
    const float* __restrict__ flow_1, const float* __restrict__ flow_2,
    const float* __restrict__ flip_flow_1, const float* __restrict__ flip_flow_2,
    const float* __restrict__ flow_cn2, const float* __restrict__ flow_n2c,
    unsigned short* __restrict__ attn_pad, int vb, char* smraw)
{
    unsigned short* vlds = (unsigned short*)smraw;                 // 49152 B
    unsigned short (*pwlds)[432] = (unsigned short(*)[432])(smraw + 49152);
    const int tid = threadIdx.x;
    const int wav = tid >> 6, lane = tid & 63;
    const int m = vb & 7, qc = vb >> 3;

    __syncthreads();
    for (int i = tid; i < 3072; i += 256) {
        int l = i >> 10, p = i & 1023;
        *(bf16x8*)(&vlds[(size_t)i * 8]) =
            *(const bf16x8*)(value_b + ((size_t)((l * 8 + m) * 1024) + p) * 8);
    }
    __syncthreads();

    const int pp = lane & 15, gq = lane >> 4;
    const int gdy = (gq >> 1) * 2 - 1;
    const int gdx = (gq & 1) * 2 - 1;
    const bool selx = (gq & 1);
    const bool sely = (gq >> 1);

    for (int r = 0; r < 8; ++r) {
        const int q = qc * 32 + r * 4 + wav;
        const int f = q >> 10, pix = q & 1023;
        const int y = pix >> 5, x = pix & 31;

        float flx0 = 0.f, fly0 = 0.f, flx1 = 0.f, fly1 = 0.f, flx2 = 0.f, fly2 = 0.f;
        if (f == 0) {
            flx1 = flow_1[pix];      fly1 = flow_1[HW + pix];
            flx2 = flow_cn2[pix];    fly2 = flow_cn2[HW + pix];
        } else if (f == 1) {
            flx0 = flip_flow_1[pix]; fly0 = flip_flow_1[HW + pix];
            flx2 = flow_2[pix];      fly2 = flow_2[HW + pix];
        } else {
            flx0 = flow_n2c[pix];    fly0 = flow_n2c[HW + pix];
            flx1 = flip_flow_2[pix]; fly1 = flip_flow_2[HW + pix];
        }

        const unsigned short* awp = aw_t + (size_t)q * 2592 + m * 324;
        float av[6];
        float vmax = -1e30f;
#pragma unroll
        for (int it = 0; it < 6; ++it) {
            int j = lane + it * 64;
            float a = (j < 324) ? bf2f(awp[j]) : -1e30f;
            av[it] = a;
            vmax = fmaxf(vmax, a);
        }
#pragma unroll
        for (int off = 32; off; off >>= 1) vmax = fmaxf(vmax, __shfl_xor(vmax, off));
        float ssum = 0.f;
#pragma unroll
        for (int it = 0; it < 6; ++it) {
            int j = lane + it * 64;
            float e = (j < 324) ? __expf(av[it] - vmax) : 0.f;
            av[it] = e;
            ssum += e;
        }
#pragma unroll
        for (int off = 32; off; off >>= 1) ssum += __shfl_xor(ssum, off);
        const float inv = 1.f / ssum;

#pragma unroll
        for (int it = 0; it < 6; ++it) {
            int j = lane + it * 64;
            if (j < 324) {
                int pi = j / 9, k = j - pi * 9;
                pwlds[wav][pi * 12 + k] = f2bf(av[it] * inv);
            }
        }

        float acc[8];
#pragma unroll
        for (int dd = 0; dd < 8; ++dd) acc[dd] = 0.f;
        const float* sop = so_t + (size_t)q * 576 + m * 72;

#pragma unroll
        for (int pt = 0; pt < 3; ++pt) {
            int pi = pt * 16 + pp;
            if (pi < 36) {
                int l = pi / 12;
                float2 so2 = *(const float2*)(sop + pi * 2);
                float fx = (l == 0) ? flx0 : (l == 1) ? flx1 : flx2;
                float fy = (l == 0) ? fly0 : (l == 1) ? fly1 : fly2;
                float bxf = (float)x + so2.x + fx;
                float byf = (float)y + so2.y + fy;
                float x0f = floorf(bxf), y0f = floorf(byf);
                float wx = bxf - x0f, wy = byf - y0f;
                float ax = 1.f - wx, ay = 1.f - wy;
                int x0 = (int)fminf(fmaxf(x0f, -2.f), 34.f);
                int y0 = (int)fminf(fmaxf(y0f, -2.f), 34.f);

                const unsigned short* pr = &pwlds[wav][pi * 12];
                uint2 pv0 = *(const uint2*)(pr);
                uint2 pv1 = *(const uint2*)(pr + 4);
                float a0 = bflo(pv0.x), a1 = bfhi(pv0.x), a2 = bflo(pv0.y);
                float a3 = bfhi(pv0.y), a4 = bflo(pv1.x), a5 = bfhi(pv1.x);
                float a6 = bflo(pv1.y), a7 = bfhi(pv1.y), a8 = bf2f(pr[8]);

                float bs0a, bs0b, bs1a, bs1b, bs2a, bs2b;
                {
                    float b0, b1, b2, b3;
                    b0 = a0 * ax; b1 = a0 * wx + a3 * ax; b2 = a3 * wx + a6 * ax; b3 = a6 * wx;
                    bs0a = selx ? b2 : b0; bs0b = selx ? b3 : b1;
                    b0 = a1 * ax; b1 = a1 * wx + a4 * ax; b2 = a4 * wx + a7 * ax; b3 = a7 * wx;
                    bs1a = selx ? b2 : b0; bs1b = selx ? b3 : b1;
                    b0 = a2 * ax; b1 = a2 * wx + a5 * ax; b2 = a5 * wx + a8 * ax; b3 = a8 * wx;
                    bs2a = selx ? b2 : b0; bs2b = selx ? b3 : b1;
                }
                float c00, c01, c10, c11;
                {
                    float c0 = bs0a * ay, c1 = bs0a * wy + bs1a * ay;
                    float c2 = bs1a * wy + bs2a * ay, c3 = bs2a * wy;
                    c00 = sely ? c2 : c0; c10 = sely ? c3 : c1;
                    c0 = bs0b * ay; c1 = bs0b * wy + bs1b * ay;
                    c2 = bs1b * wy + bs2b * ay; c3 = bs2b * wy;
                    c01 = sely ? c2 : c0; c11 = sely ? c3 : c1;
                }
                float cg[2][2] = {{c00, c01}, {c10, c11}};
                const int vbase = l * 1024;
#pragma unroll
                for (int sy = 0; sy < 2; ++sy) {
#pragma unroll
                    for (int sx = 0; sx < 2; ++sx) {
                        int dy = gdy + sy, dx = gdx + sx;
                        float pyf = y0f + (float)dy, pxf = x0f + (float)dx;
                        bool v = (pxf >= 0.f) && (pxf <= 31.f) && (pyf >= 0.f) && (pyf <= 31.f);
                        int px = min(max(x0 + dx, 0), 31);
                        int py = min(max(y0 + dy, 0), 31);
                        float c = cg[sy][sx] * (v ? 1.f : 0.f);
                        uint4 vv = *(const uint4*)(&vlds[(size_t)(vbase + py * 32 + px) * 8]);
                        acc[0] = fmaf(c, bflo(vv.x), acc[0]);
                        acc[1] = fmaf(c, bfhi(vv.x), acc[1]);
                        acc[2] = fmaf(c, bflo(vv.y), acc[2]);
                        acc[3] = fmaf(c, bfhi(vv.y), acc[3]);
                        acc[4] = fmaf(c, bflo(vv.z), acc[4]);
                        acc[5] = fmaf(c, bfhi(vv.z), acc[5]);
                        acc[6] = fmaf(c, bflo(vv.w), acc[6]);
                        acc[7] = fmaf(c, bfhi(vv.w), acc[7]);
                    }
                }
            }
        }

#pragma unroll
        for (int dd = 0; dd < 8; ++dd) {
#pragma unroll
            for (int off = 32; off; off >>= 1) acc[dd] += __shfl_xor(acc[dd], off);
        }
        if (lane == 0) {
            unsigned short* op = attn_pad + (size_t)((y + 1) * 34 + x + 1) * 192 + f * 64 + m * 8;
            ushort4 s0, s1;
            s0.x = f2bf(acc[0]); s0.y = f2bf(acc[1]); s0.z = f2bf(acc[2]); s0.w = f2bf(acc[3]);
            s1.x = f2bf(acc[4]); s1.y = f2bf(acc[5]); s1.z = f2bf(acc[6]); s1.w = f2bf(acc[7]);
            *(ushort4*)(op) = s0;
            *(ushort4*)(op + 4) = s1;
        }
    }
}

// ---------------------------------------------------------------------------
// Megakernel: 768 persistent blocks (3/CU by LDS), 8 phases, 7 grid barriers.
// ---------------------------------------------------------------------------
__global__ __launch_bounds__(256, 3) void mega_k(MegaA A) {
    __shared__ __align__(16) char sm[SMEM_BYTES];
    // workspace layout (must match host)
    float* flow_cn2 = (float*)A.ws;
    float* flow_n2c = flow_cn2 + 2048;
    unsigned short* value_b = (unsigned short*)(flow_n2c + 2048);
    float* so_t = (float*)(value_b + 196608);
    unsigned short* x_pad = (unsigned short*)(so_t + 1769472);
    unsigned short* vp0h      = x_pad + 1156 * 192;
    unsigned short* extra_pad = vp0h + 1156 * 192;
    unsigned short* s1 = extra_pad + 1156 * 480;
    unsigned short* a1 = s1 + 1156 * 64;
    unsigned short* s2 = a1 + 1156 * 64;
    unsigned short* a2 = s2 + 1156 * 64;
    unsigned short* attn_pad = a2 + 1156 * 64;
    unsigned short* op0h = attn_pad + 1156 * 192;
    unsigned short* aw_t = op0h + 1156 * 192;
    unsigned short* wgt = aw_t + (size_t)3072 * 2592;
    int* bar = A.bar;

    // ---- phase 0: prep ----
    for (int vb = blockIdx.x; vb < 3776; vb += GRID)
        prep_tile(A, flow_cn2, flow_n2c, x_pad, extra_pad, wgt, vb, sm);
    grid_bar(bar, 0);

    // ---- phase 1: vp0 + so0 + aw0 ----
    for (int vb = blockIdx.x; vb < 160; vb += GRID) {
        int bx = vb >> 3, by = vb & 7;
        CDesc d;
        if (bx < 12)      { d = {x_pad, wgt, A.wp[1], vp0h, nullptr, 192, 6, 192, 3, 192, 1}; }
        else if (bx < 16) { d = {extra_pad, wgt + (size_t)1296 * 512, A.wp[13], a1, nullptr, 480, 15, 64, 3, 64, 1};
                            // NOTE: descriptor order — see below; so0 first
                            d = {extra_pad, wgt + (size_t)1296 * 512, A.wp[5], s1, nullptr, 480, 15, 64, 3, 64, 1}; bx -= 12; }
        else              { d = {extra_pad, wgt + (size_t)1836 * 512, A.wp[13], a1, nullptr, 480, 15, 64, 3, 64, 1}; bx -= 16; }
        conv_tile<4, 16>(d, bx, by, sm);
    }
    grid_bar(bar, 1);

    // ---- phase 2: vp1 + so1 + aw1 ----
    for (int vb = blockIdx.x; vb < 160; vb += GRID) {
        int bx = vb >> 3, by = vb & 7;
        CDesc d;
        if (bx < 12)      { d = {vp0h, wgt + (size_t)648 * 512, A.wp[3], value_b, nullptr, 192, 6, 192, 2, 8, 0}; }
        else if (bx < 16) { d = {s1, wgt + (size_t)2376 * 512, A.wp[7], s2, nullptr, 64, 2, 64, 3, 64, 1}; bx -= 12; }
        else              { d = {a1, wgt + (size_t)2448 * 512, A.wp[15], a2, nullptr, 64, 2, 64, 3, 64, 1}; bx -= 16; }
        conv_tile<4, 16>(d, bx, by, sm);
    }
    grid_bar(bar, 2);

    // ---- phase 3: so2 + aw2 ----
    for (int vb = blockIdx.x; vb < 64; vb += GRID) {
        int bx = vb >> 3, by = vb & 7;
        CDesc d;
        if (bx < 4) { d = {s2, wgt + (size_t)2520 * 512, A.wp[9], s1, nullptr, 64, 2, 64, 3, 64, 1}; }
        else        { d = {a2, wgt + (size_t)2592 * 512, A.wp[17], a1, nullptr, 64, 2, 64, 3, 64, 1}; bx -= 4; }
        conv_tile<4, 16>(d, bx, by, sm);
    }
    grid_bar(bar, 3);

    // ---- phase 4: so3 + aw3 (COBLK=32) ----
    for (int vb = blockIdx.x; vb < 1188; vb += GRID) {
        int bx = vb >> 2, by = vb & 3;
        CDesc d;
        if (bx < 54) { d = {s1, wgt + (size_t)2664 * 512, A.wp[11], so_t, nullptr, 64, 2, 1728, 1, 576, 0}; }
        else         { d = {a1, wgt + (size_t)4608 * 512, A.wp[19], aw_t, nullptr, 64, 2, 7776, 2, 2592, 0}; bx -= 54; }
        conv_tile<8, 32>(d, bx, by, sm);
    }
    grid_bar(bar, 4);

    // ---- phase 5: deformable attention (exactly 1 vb per block) ----
    for (int vb = blockIdx.x; vb < 768; vb += GRID)
        attn_tile(value_b, so_t, aw_t, A.f1, A.f2, A.ff1, A.ff2,
                  flow_cn2, flow_n2c, attn_pad, vb, sm);
    grid_bar(bar, 5);

    // ---- phase 6: op0 ----
    for (int vb = blockIdx.x; vb < 96; vb += GRID) {
        int bx = vb >> 3, by = vb & 7;
        CDesc d = {attn_pad, wgt + (size_t)13392 * 512, A.wp[21], op0h, nullptr, 192, 6, 192, 3, 192, 1};
        conv_tile<4, 16>(d, bx, by, sm);
    }
    grid_bar(bar, 6);

    // ---- phase 7: op1 + residual ----
    for (int vb = blockIdx.x; vb < 96; vb += GRID) {
        int bx = vb >> 3, by = vb & 7;
        CDesc d = {op0h, wgt + (size_t)14040 * 512, A.wp[23], A.out, A.x, 192, 6, 192, 0, 0, 0};
        conv_tile<4, 16>(d, bx, by, sm);
    }
}

// ---------------------------------------------------------------------------
extern "C" void kernel_launch(void* const* d_in, const int* in_sizes, int n_in,
                              void* d_out, int out_size, void* d_ws, size_t ws_size,
                              hipStream_t stream) {
    (void)in_sizes; (void)n_in; (void)out_size; (void)ws_size;

    MegaA A;
    A.x   = (const float*)d_in[0];
    A.f1  = (const float*)d_in[1];
    A.f2  = (const float*)d_in[2];
    A.ff1 = (const float*)d_in[3];
    A.ff2 = (const float*)d_in[4];
    for (int i = 0; i < 24; ++i) A.wp[i] = (const float*)d_in[5 + i];
    A.out = (float*)d_out;
    A.ws  = (char*)d_ws;

    // barrier state at end of workspace layout
    size_t off = 0;
    off += (size_t)4096 * 4;               // flows (2x2048 floats)
    off += (size_t)196608 * 2;             // value_b
    off += (size_t)1769472 * 4;            // so_t
    off += (size_t)1156 * 1504 * 2;        // padded bf16 buffers
    off += (size_t)3072 * 2592 * 2;        // aw_t
    off += (size_t)14688 * 512 * 2;        // wgt
    int* bar = (int*)(A.ws + off);
    A.bar = bar;

    hipMemsetAsync(bar, 0, 8 * 16 * sizeof(int), stream);
    hipLaunchKernelGGL(mega_k, dim3(GRID), dim3(256), 0, stream, A);
}

// Round 10
// 284.225 us; speedup vs baseline: 2.8147x; 2.8147x over previous
//
#include <hip/hip_runtime.h>
#include <math.h>

#define HW 1024

typedef __attribute__((ext_vector_type(8))) short bf16x8;
typedef __attribute__((ext_vector_type(4))) float floatx4;

__device__ __forceinline__ unsigned short f2bf(float f) {
    unsigned u = __float_as_uint(f);
    u += 0x7FFF + ((u >> 16) & 1);
    return (unsigned short)(u >> 16);
}
__device__ __forceinline__ float bf2f(unsigned short u) {
    return __uint_as_float(((unsigned)u) << 16);
}
__device__ __forceinline__ float bflo(unsigned u) { return __uint_as_float(u << 16); }
__device__ __forceinline__ float bfhi(unsigned u) { return __uint_as_float(u & 0xffff0000u); }

// ---------------------------------------------------------------------------
// Bilinear sample, zero padding, absolute pixel coords (matches reference).
// ---------------------------------------------------------------------------
__device__ __forceinline__ float bilin32(const float* __restrict__ img, float px, float py) {
    float x0f = floorf(px), y0f = floorf(py);
    float wx = px - x0f, wy = py - y0f;
    bool vx0 = (x0f >= 0.f) && (x0f <= 31.f);
    bool vx1 = (x0f >= -1.f) && (x0f <= 30.f);
    bool vy0 = (y0f >= 0.f) && (y0f <= 31.f);
    bool vy1 = (y0f >= -1.f) && (y0f <= 30.f);
    int ix0 = (int)fminf(fmaxf(x0f, 0.f), 31.f);
    int iy0 = (int)fminf(fmaxf(y0f, 0.f), 31.f);
    int ix1 = (int)fminf(fmaxf(x0f + 1.f, 0.f), 31.f);
    int iy1 = (int)fminf(fmaxf(y0f + 1.f, 0.f), 31.f);
    float w00 = (1.f - wx) * (1.f - wy) * ((vx0 && vy0) ? 1.f : 0.f);
    float w01 = wx * (1.f - wy) * ((vx1 && vy0) ? 1.f : 0.f);
    float w10 = (1.f - wx) * wy * ((vx0 && vy1) ? 1.f : 0.f);
    float w11 = wx * wy * ((vx1 && vy1) ? 1.f : 0.f);
    return w00 * img[iy0 * 32 + ix0] + w01 * img[iy0 * 32 + ix1] +
           w10 * img[iy1 * 32 + ix0] + w11 * img[iy1 * 32 + ix1];
}

__device__ __forceinline__ float2 comp_flow(const float* __restrict__ fa,
                                            const float* __restrict__ fb, int pix) {
    int y = pix >> 5, x = pix & 31;
    float fx = fa[pix], fy = fa[HW + pix];
    float px = (float)x + fx, py = (float)y + fy;
    float2 r;
    r.x = fx + bilin32(fb, px, py);
    r.y = fy + bilin32(fb + HW, px, py);
    return r;
}

// ---------------------------------------------------------------------------
// Prep kernel (round-8): xpad / build_extra / flows / borders / wxform.
// ---------------------------------------------------------------------------
struct WD { const float* src; int cout, Cin, nCb, wbase, beg; };
struct PrepP {
    const float *x, *f1, *f2, *ff1, *ff2;
    float *fcn2, *fn2c;
    unsigned short *x_pad, *extra_pad, *wgt;
    WD wd[12];
};

__global__ __launch_bounds__(256) void prep_k(PrepP P) {
    __shared__ float wlds[16 * 288];
    const int b = blockIdx.x, tid = threadIdx.x;
    if (b < 192) {
        int idx = b * 256 + tid;
        int pix = idx / 48, c4 = idx - pix * 48;
        int y = pix >> 5, xx = pix & 31;
        int c0 = c4 * 4;
        ushort4 s;
        s.x = f2bf(P.x[(size_t)(c0 + 0) * HW + pix]);
        s.y = f2bf(P.x[(size_t)(c0 + 1) * HW + pix]);
        s.z = f2bf(P.x[(size_t)(c0 + 2) * HW + pix]);
        s.w = f2bf(P.x[(size_t)(c0 + 3) * HW + pix]);
        *(ushort4*)(&P.x_pad[(size_t)((y + 1) * 34 + xx + 1) * 192 + c0]) = s;
    } else if (b < 2112) {
        int idx = (b - 192) * 256 + tid;
        int ch = idx >> 10, pix = idx & 1023;
        int y = pix >> 5, xx = pix & 31;
        float v = 0.f;
        if (ch < 64) {
            v = P.x[(size_t)ch * HW + pix];
        } else if (ch < 448) {
            int grp = (ch - 64) >> 6;
            int c = (ch - 64) & 63;
            const float* src;
            float fx, fy;
            if (grp == 0)      { src = P.x + 64 * HW;  fx = P.f1[pix];  fy = P.f1[HW + pix]; }
            else if (grp == 1) { src = P.x + 128 * HW; float2 r = comp_flow(P.f1, P.f2, pix);  fx = r.x; fy = r.y; }
            else if (grp == 2) { src = P.x;            fx = P.ff1[pix]; fy = P.ff1[HW + pix]; }
            else if (grp == 3) { src = P.x + 128 * HW; fx = P.f2[pix];  fy = P.f2[HW + pix]; }
            else if (grp == 4) { src = P.x + 64 * HW;  fx = P.ff2[pix]; fy = P.ff2[HW + pix]; }
            else               { src = P.x;            float2 r = comp_flow(P.ff2, P.ff1, pix); fx = r.x; fy = r.y; }
            v = bilin32(src + c * HW, (float)xx + fx, (float)y + fy);
        } else if (ch < 460) {
            int fc = ch - 448;
            int which = fc >> 1, comp = fc & 1;
            if (which == 0)      v = P.f1[comp * HW + pix];
            else if (which == 1) { float2 r = comp_flow(P.f1, P.f2, pix);  v = comp ? r.y : r.x; }
            else if (which == 2) v = P.ff1[comp * HW + pix];
            else if (which == 3) v = P.f2[comp * HW + pix];
            else if (which == 4) v = P.ff2[comp * HW + pix];
            else                 { float2 r = comp_flow(P.ff2, P.ff1, pix); v = comp ? r.y : r.x; }
        }
        P.extra_pad[(size_t)((y + 1) * 34 + xx + 1) * 480 + ch] = f2bf(v);
    } else if (b < 2128) {
        int idx = (b - 2112) * 256 + tid;
        if (idx < 1024) {
            float2 r = comp_flow(P.f1, P.f2, idx);
            P.fcn2[idx] = r.x; P.fcn2[HW + idx] = r.y;
        } else if (idx < 2048) {
            int pix = idx - 1024;
            float2 r = comp_flow(P.ff2, P.ff1, pix);
            P.fn2c[pix] = r.x; P.fn2c[HW + pix] = r.y;
        }
    } else if (b < 2144) {
        const int chans[9] = {192, 192, 480, 64, 64, 64, 64, 192, 192};
        size_t offs[9]; size_t a = 0;
        for (int i = 0; i < 9; ++i) { offs[i] = a; a += (size_t)1156 * chans[i]; }
        int bb = b - 2128;
        for (int item = bb; item < 9 * 132; item += 16) {
            int buf = item / 132, i = item - buf * 132;
            int py, px;
            if (i < 34) { py = 0; px = i; }
            else if (i < 68) { py = 33; px = i - 34; }
            else { int j = i - 68; py = 1 + (j >> 1); px = (j & 1) ? 33 : 0; }
            int C = chans[buf];
            unsigned short* p = P.x_pad + offs[buf] + (size_t)(py * 34 + px) * C;
            for (int c = tid; c < C; c += 256) p[c] = 0;
        }
    } else {
        int blk = b - 2144;                      // < 1632
        int di = 0;
        while (di < 11 && blk >= P.wd[di + 1].beg) ++di;
        WD w = P.wd[di];
        int local = blk - w.beg;
        int co16 = local / w.nCb, cb = local - co16 * w.nCb;
        int cr0 = co16 * 16, ci0 = cb * 32;
        for (int i = tid; i < 16 * 288; i += 256) {
            int cr = i / 288, o = i - cr * 288;
            int crg = cr0 + cr, ci = ci0 + o / 9;
            float v = (crg < w.cout && ci < w.Cin)
                ? w.src[((size_t)crg * w.Cin + ci0) * 9 + o] : 0.f;
            wlds[i] = v;
        }
        __syncthreads();
        for (int e = tid; e < 9 * 512; e += 256) {
            int t = e >> 9, idx = e & 511;
            int j = idx & 7, lane = idx >> 3, q = lane >> 4, mm = lane & 15;
            P.wgt[((size_t)w.wbase + ((size_t)co16 * 9 + t) * w.nCb + cb) * 512 + idx] =
                f2bf(wlds[mm * 288 + (q * 8 + j) * 9 + t]);
        }
    }
}

// ---------------------------------------------------------------------------
// MFMA 3x3 conv tile, register-prefetch double-buffered (device function).
// ---------------------------------------------------------------------------
struct CDesc {
    const unsigned short* in;
    const unsigned short* wgt;
    const float* bias;
    void* out;
    const float* residual;
    int Cpad, nCb, Cout, mode, cmod, relu, Mblocks;
};
struct CParam { CDesc d[4]; };

template<int PIXROWS, int COBLK>
__device__ __forceinline__ void conv_tile(const CDesc d, int bx, int by, char* smraw) {
    constexpr int TROWS = PIXROWS + 2;
    constexpr int TC = TROWS * 34 * 4;
    constexpr int ITRIPS = (TC + 255) / 256;
    constexpr int NTY = PIXROWS / 4;
    constexpr int NACC = NTY * 2;
    constexpr int MT = COBLK / 16;
    constexpr int WN = MT * 9 * 64;
    constexpr int WTRIPS = (WN + 255) / 256;
    unsigned short* blds = (unsigned short*)smraw;
    unsigned short* wlds = (unsigned short*)(smraw + TROWS * 34 * 40 * 2);

    const int tid = threadIdx.x;
    const int w = tid >> 6, lane = tid & 63;
    const int lq = lane >> 4, ln = lane & 15;
    const int co0 = bx * COBLK;
    const int y0 = by * PIXROWS;
    const unsigned short* __restrict__ in = d.in;
    const unsigned short* __restrict__ wg = d.wgt;
    const int Cpad = d.Cpad, nCb = d.nCb;

    floatx4 acc[MT][NACC];
#pragma unroll
    for (int mt = 0; mt < MT; ++mt)
#pragma unroll
        for (int nt = 0; nt < NACC; ++nt)
            acc[mt][nt] = (floatx4){0.f, 0.f, 0.f, 0.f};

    bf16x8 ireg[ITRIPS];
    bf16x8 wreg[WTRIPS];

    auto load_regs = [&](int cb) {
        const int ci0 = cb << 5;
#pragma unroll
        for (int k = 0; k < ITRIPS; ++k) {
            int i = tid + k * 256;
            if (i < TC) {
                int r = i / 136, rem = i - r * 136, c = rem >> 2, g = rem & 3;
                ireg[k] = *(const bf16x8*)(in + (size_t)((y0 + r) * 34 + c) * Cpad + ci0 + g * 8);
            }
        }
#pragma unroll
        for (int k = 0; k < WTRIPS; ++k) {
            int i = tid + k * 256;
            if (i < WN) {
                int chunk = i >> 6, l16 = i & 63;
                int mt = chunk / 9, t = chunk - mt * 9;
                wreg[k] = *(const bf16x8*)(wg + ((size_t)(((co0 >> 4) + mt) * 9 + t) * nCb + cb) * 512 + l16 * 8);
            }
        }
    };

    load_regs(0);

    for (int cb = 0; cb < nCb; ++cb) {
        __syncthreads();
#pragma unroll
        for (int k = 0; k < ITRIPS; ++k) {
            int i = tid + k * 256;
            if (i < TC) {
                int r = i / 136, rem = i - r * 136, c = rem >> 2, g = rem & 3;
                *(bf16x8*)(&blds[(r * 34 + c) * 40 + g * 8]) = ireg[k];
            }
        }
#pragma unroll
        for (int k = 0; k < WTRIPS; ++k) {
            int i = tid + k * 256;
            if (i < WN) {
                int chunk = i >> 6, l16 = i & 63;
                *(bf16x8*)(&wlds[chunk * 512 + l16 * 8]) = wreg[k];
            }
        }
        __syncthreads();
        if (cb + 1 < nCb) load_regs(cb + 1);
        for (int t = 0; t < 9; ++t) {
            const int dy = t / 3, dx = t - dy * 3;
            bf16x8 bfr[NACC];
#pragma unroll
            for (int ty = 0; ty < NTY; ++ty)
#pragma unroll
                for (int tx = 0; tx < 2; ++tx) {
                    int yy = w * NTY + ty + dy;
                    int xx = tx * 16 + ln + dx;
                    bfr[ty * 2 + tx] = *(const bf16x8*)(&blds[(yy * 34 + xx) * 40 + lq * 8]);
                }
#pragma unroll
            for (int mt = 0; mt < MT; ++mt) {
                bf16x8 afr = *(const bf16x8*)(&wlds[(mt * 9 + t) * 512 + lane * 8]);
#pragma unroll
                for (int nt = 0; nt < NACC; ++nt)
                    acc[mt][nt] = __builtin_amdgcn_mfma_f32_16x16x32_bf16(afr, bfr[nt], acc[mt][nt], 0, 0, 0);
            }
        }
    }

#pragma unroll
    for (int mt = 0; mt < MT; ++mt) {
        const int co = co0 + mt * 16 + lq * 4;
        if (co >= d.Cout) continue;
        float bv[4];
#pragma unroll
        for (int r = 0; r < 4; ++r) bv[r] = d.bias[co + r];
#pragma unroll
        for (int nt = 0; nt < NACC; ++nt) {
            const int ty = nt >> 1, tx = nt & 1;
            const int pix = by * (PIXROWS * 32) + (w * NTY + ty) * 32 + tx * 16 + ln;
            float v[4];
#pragma unroll
            for (int r = 0; r < 4; ++r) {
                float vv = acc[mt][nt][r] + bv[r];
                if (d.relu) vv = (vv >= 0.f) ? vv : 0.1f * vv;
                v[r] = vv;
            }
            if (d.mode == 0) {
                float* o = (float*)d.out;
#pragma unroll
                for (int r = 0; r < 4; ++r) {
                    float vv = v[r];
                    if (d.residual) vv += d.residual[(size_t)(co + r) * HW + pix];
                    o[(size_t)(co + r) * HW + pix] = vv;
                }
            } else if (d.mode == 1) {
                int fq = co / d.cmod, cc = co - fq * d.cmod;
                *(float4*)((float*)d.out + ((size_t)fq * HW + pix) * d.cmod + cc) =
                    make_float4(v[0], v[1], v[2], v[3]);
            } else if (d.mode == 2) {
                int fq = co / d.cmod, cc = co - fq * d.cmod;
                ushort4 s4;
                s4.x = f2bf(v[0]); s4.y = f2bf(v[1]); s4.z = f2bf(v[2]); s4.w = f2bf(v[3]);
                *(ushort4*)((unsigned short*)d.out + ((size_t)fq * HW + pix) * d.cmod + cc) = s4;
            } else {
                int yy = (pix >> 5) + 1, xx = (pix & 31) + 1;
                ushort4 s4;
                s4.x = f2bf(v[0]); s4.y = f2bf(v[1]); s4.z = f2bf(v[2]); s4.w = f2bf(v[3]);
                *(ushort4*)((unsigned short*)d.out + (size_t)(yy * 34 + xx) * d.cmod + co) = s4;
            }
        }
    }
}

// Standalone multi-descriptor conv dispatch wrapper.
template<int PIXROWS, int COBLK>
__global__ __launch_bounds__(256) void conv_mfma_k(CParam P) {
    constexpr int TROWS = PIXROWS + 2;
    constexpr int MT = COBLK / 16;
    __shared__ __align__(16) char sm[TROWS * 34 * 40 * 2 + MT * 9 * 512 * 2];
    int bx = blockIdx.x;
    int di = 0;
    while (bx >= P.d[di].Mblocks) { bx -= P.d[di].Mblocks; ++di; }
    conv_tile<PIXROWS, COBLK>(P.d[di], bx, blockIdx.y, sm);
}

// ---------------------------------------------------------------------------
// Fused 64->conv(lrelu)->64->conv(lrelu)->64 chain (so1+so2 or aw1+aw2).
// One block = 4 output rows (full width). Stage 1 computes 6 rows (1-row
// y-halo; out-of-image rows are zeros by SAME-conv convention) into LDS
// [6][34][72] bf16 with zero x-borders; stage 2 convolves from LDS.
// No inter-block communication -> no grid barrier needed.
// ---------------------------------------------------------------------------
struct FDesc {
    const unsigned short* in;   // padded [34*34][64]
    const unsigned short* w1;   // frag weights, nCb=2
    const float* b1;
    const unsigned short* w2;
    const float* b2;
    unsigned short* out;        // padded [34*34][64]
};

__device__ __forceinline__ void fused2_tile(const FDesc d, int by, char* smraw) {
    unsigned short* blds = (unsigned short*)smraw;                   // 8*34*40
    unsigned short* ilds = (unsigned short*)(smraw + 21760);         // 6*34*72
    unsigned short* wlds = (unsigned short*)(smraw + 21760 + 29376); // 36*512
    const int tid = threadIdx.x;
    const int w = tid >> 6, lane = tid & 63;
    const int lq = lane >> 4, ln = lane & 15;
    const int y0 = by * 4;

    // ---- stage 1: rows y0-1 .. y0+4 (r=0..5), 192 positions, 12 ntiles ----
    floatx4 acc1[4][3];
#pragma unroll
    for (int mt = 0; mt < 4; ++mt)
#pragma unroll
        for (int nt = 0; nt < 3; ++nt)
            acc1[mt][nt] = (floatx4){0.f, 0.f, 0.f, 0.f};

    for (int cb = 0; cb < 2; ++cb) {
        __syncthreads();
        for (int i = tid; i < 1088; i += 256) {          // 8 rows x 34 x 4 chunks
            int r = i / 136, rem = i - r * 136, c = rem >> 2, g = rem & 3;
            int pr = min(max(y0 - 1 + r, 0), 33);        // padded row (clamped)
            *(bf16x8*)(&blds[(r * 34 + c) * 40 + g * 8]) =
                *(const bf16x8*)(d.in + (size_t)(pr * 34 + c) * 64 + cb * 32 + g * 8);
        }
        for (int i = tid; i < 2304; i += 256) {          // 36 frag blocks x 64
            int chunk = i >> 6, l16 = i & 63;
            int mt = chunk / 9, t = chunk - mt * 9;
            *(bf16x8*)(&wlds[chunk * 512 + l16 * 8]) =
                *(const bf16x8*)(d.w1 + ((size_t)(mt * 9 + t) * 2 + cb) * 512 + l16 * 8);
        }
        __syncthreads();
        for (int t = 0; t < 9; ++t) {
            int dy = t / 3, dx = t - dy * 3;
            bf16x8 bfr[3];
#pragma unroll
            for (int nt = 0; nt < 3; ++nt) {
                int p = (w * 3 + nt) * 16 + ln;          // position 0..191
                int r = p >> 5, col = p & 31;
                bfr[nt] = *(const bf16x8*)(&blds[((r + dy) * 34 + col + dx) * 40 + lq * 8]);
            }
#pragma unroll
            for (int mt = 0; mt < 4; ++mt) {
                bf16x8 afr = *(const bf16x8*)(&wlds[(mt * 9 + t) * 512 + lane * 8]);
#pragma unroll
                for (int nt = 0; nt < 3; ++nt)
                    acc1[mt][nt] = __builtin_amdgcn_mfma_f32_16x16x32_bf16(afr, bfr[nt], acc1[mt][nt], 0, 0, 0);
            }
        }
    }
    __syncthreads();
    // zero x-borders of ilds (cols 0, 33): 6 rows x 2 cols x 16 ushort4
    for (int i = tid; i < 192; i += 256) {
        int rr = i / 32, rem = i - rr * 32;
        int side = rem >> 4, c4 = rem & 15;
        int col = side ? 33 : 0;
        ushort4 z; z.x = 0; z.y = 0; z.z = 0; z.w = 0;
        *(ushort4*)(&ilds[(rr * 34 + col) * 72 + c4 * 4]) = z;
    }
    // write stage-1 results (lrelu + row-validity mask)
#pragma unroll
    for (int mt = 0; mt < 4; ++mt) {
        int co = mt * 16 + lq * 4;
        float bv[4];
#pragma unroll
        for (int r = 0; r < 4; ++r) bv[r] = d.b1[co + r];
#pragma unroll
        for (int nt = 0; nt < 3; ++nt) {
            int p = (w * 3 + nt) * 16 + ln;
            int r = p >> 5, col = p & 31;
            int yi = y0 - 1 + r;
            float msk = (yi >= 0 && yi <= 31) ? 1.f : 0.f;
            ushort4 s4;
            float v0 = acc1[mt][nt][0] + bv[0]; v0 = (v0 >= 0.f) ? v0 : 0.1f * v0;
            float v1 = acc1[mt][nt][1] + bv[1]; v1 = (v1 >= 0.f) ? v1 : 0.1f * v1;
            float v2 = acc1[mt][nt][2] + bv[2]; v2 = (v2 >= 0.f) ? v2 : 0.1f * v2;
            float v3 = acc1[mt][nt][3] + bv[3]; v3 = (v3 >= 0.f) ? v3 : 0.1f * v3;
            s4.x = f2bf(v0 * msk); s4.y = f2bf(v1 * msk);
            s4.z = f2bf(v2 * msk); s4.w = f2bf(v3 * msk);
            *(ushort4*)(&ilds[(r * 34 + col + 1) * 72 + co]) = s4;
        }
    }
    __syncthreads();

    // ---- stage 2: 4 output rows (wave w -> row y0+w), cols via 2 ntiles ----
    floatx4 acc2[4][2];
#pragma unroll
    for (int mt = 0; mt < 4; ++mt)
#pragma unroll
        for (int nt = 0; nt < 2; ++nt)
            acc2[mt][nt] = (floatx4){0.f, 0.f, 0.f, 0.f};

    for (int cb = 0; cb < 2; ++cb) {
        __syncthreads();
        for (int i = tid; i < 2304; i += 256) {
            int chunk = i >> 6, l16 = i & 63;
            int mt = chunk / 9, t = chunk - mt * 9;
            *(bf16x8*)(&wlds[chunk * 512 + l16 * 8]) =
                *(const bf16x8*)(d.w2 + ((size_t)(mt * 9 + t) * 2 + cb) * 512 + l16 * 8);
        }
        __syncthreads();
        for (int t = 0; t < 9; ++t) {
            int dy = t / 3, dx = t - dy * 3;
            bf16x8 bfr[2];
#pragma unroll
            for (int nt = 0; nt < 2; ++nt) {
                int col = nt * 16 + ln;
                int r = w + dy;                          // ilds row 0..5
                bfr[nt] = *(const bf16x8*)(&ilds[(r * 34 + col + dx) * 72 + cb * 32 + lq * 8]);
            }
#pragma unroll
            for (int mt = 0; mt < 4; ++mt) {
                bf16x8 afr = *(const bf16x8*)(&wlds[(mt * 9 + t) * 512 + lane * 8]);
#pragma unroll
                for (int nt = 0; nt < 2; ++nt)
                    acc2[mt][nt] = __builtin_amdgcn_mfma_f32_16x16x32_bf16(afr, bfr[nt], acc2[mt][nt], 0, 0, 0);
            }
        }
    }
    // epilogue: lrelu, padded bf16 out
#pragma unroll
    for (int mt = 0; mt < 4; ++mt) {
        int co = mt * 16 + lq * 4;
        float bv[4];
#pragma unroll
        for (int r = 0; r < 4; ++r) bv[r] = d.b2[co + r];
#pragma unroll
        for (int nt = 0; nt < 2; ++nt) {
            int col = nt * 16 + ln;
            int yo = y0 + w;
            ushort4 s4;
            float v0 = acc2[mt][nt][0] + bv[0]; v0 = (v0 >= 0.f) ? v0 : 0.1f * v0;
            float v1 = acc2[mt][nt][1] + bv[1]; v1 = (v1 >= 0.f) ? v1 : 0.1f * v1;
            float v2 = acc2[mt][nt][2] + bv[2]; v2 = (v2 >= 0.f) ? v2 : 0.1f * v2;
            float v3 = acc2[mt][nt][3] + bv[3]; v3 = (v3 >= 0.f) ? v3 : 0.1f * v3;
            s4.x = f2bf(v0); s4.y = f2bf(v1); s4.z = f2bf(v2); s4.w = f2bf(v3);
            *(ushort4*)(&d.out[(size_t)((yo + 1) * 34 + col + 1) * 64 + co]) = s4;
        }
    }
}

// Dispatch L2': vp1 (bx 0..11) + fused so-chain (bx 12) + fused aw-chain (bx 13).
struct L2FParam { CDesc vp1; FDesc so; FDesc aw; };

__global__ __launch_bounds__(256) void l2f_k(L2FParam P) {
    __shared__ __align__(16) char sm[21760 + 29376 + 36864];
    if (blockIdx.x < 12)       conv_tile<4, 16>(P.vp1, blockIdx.x, blockIdx.y, sm);
    else if (blockIdx.x == 12) fused2_tile(P.so, blockIdx.y, sm);
    else                       fused2_tile(P.aw, blockIdx.y, sm);
}

// ---------------------------------------------------------------------------
// Deformable attention (round-8: LDS value + patch-convolution gathers).
// ---------------------------------------------------------------------------
__global__ __launch_bounds__(256) void deform_attn_k(
    const unsigned short* __restrict__ value_b, const float* __restrict__ so_t,
    const unsigned short* __restrict__ aw_t,
    const float* __restrict__ flow_1, const float* __restrict__ flow_2,
    const float* __restrict__ flip_flow_1, const float* __restrict__ flip_flow_2,
    const float* __restrict__ flow_cn2, const float* __restrict__ flow_n2c,
    unsigned short* __restrict__ attn_pad)
{
    __shared__ unsigned short vlds[24576];
    __shared__ unsigned short pwlds[4][432];
    const int tid = threadIdx.x;
    const int wav = tid >> 6, lane = tid & 63;
    const int m = blockIdx.x & 7, qc = blockIdx.x >> 3;

    for (int i = tid; i < 3072; i += 256) {
        int l = i >> 10, p = i & 1023;
        *(bf16x8*)(&vlds[(size_t)i * 8]) =
            *(const bf16x8*)(value_b + ((size_t)((l * 8 + m) * 1024) + p) * 8);
    }
    __syncthreads();

    const int pp = lane & 15, gq = lane >> 4;
    const int gdy = (gq >> 1) * 2 - 1;
    const int gdx = (gq & 1) * 2 - 1;
    const bool selx = (gq & 1);
    const bool sely = (gq >> 1);

    for (int r = 0; r < 8; ++r) {
        const int q = qc * 32 + r * 4 + wav;
        const int f = q >> 10, pix = q & 1023;
        const int y = pix >> 5, x = pix & 31;

        float flx0 = 0.f, fly0 = 0.f, flx1 = 0.f, fly1 = 0.f, flx2 = 0.f, fly2 = 0.f;
        if (f == 0) {
            flx1 = flow_1[pix];      fly1 = flow_1[HW + pix];
            flx2 = flow_cn2[pix];    fly2 = flow_cn2[HW + pix];
        } else if (f == 1) {
            flx0 = flip_flow_1[pix]; fly0 = flip_flow_1[HW + pix];
            flx2 = flow_2[pix];      fly2 = flow_2[HW + pix];
        } else {
            flx0 = flow_n2c[pix];    fly0 = flow_n2c[HW + pix];
            flx1 = flip_flow_2[pix]; fly1 = flip_flow_2[HW + pix];
        }

        const unsigned short* awp = aw_t + (size_t)q * 2592 + m * 324;
        float av[6];
        float vmax = -1e30f;
#pragma unroll
        for (int it = 0; it < 6; ++it) {
            int j = lane + it * 64;
            float a = (j < 324) ? bf2f(awp[j]) : -1e30f;
            av[it] = a;
            vmax = fmaxf(vmax, a);
        }
#pragma unroll
        for (int off = 32; off; off >>= 1) vmax = fmaxf(vmax, __shfl_xor(vmax, off));
        float ssum = 0.f;
#pragma unroll
        for (int it = 0; it < 6; ++it) {
            int j = lane + it * 64;
            float e = (j < 324) ? __expf(av[it] - vmax) : 0.f;
            av[it] = e;
            ssum += e;
        }
#pragma unroll
        for (int off = 32; off; off >>= 1) ssum += __shfl_xor(ssum, off);
        const float inv = 1.f / ssum;

#pragma unroll
        for (int it = 0; it < 6; ++it) {
            int j = lane + it * 64;
            if (j < 324) {
                int pi = j / 9, k = j - pi * 9;
                pwlds[wav][pi * 12 + k] = f2bf(av[it] * inv);
            }
        }

        float acc[8];
#pragma unroll
        for (int dd = 0; dd < 8; ++dd) acc[dd] = 0.f;
        const float* sop = so_t + (size_t)q * 576 + m * 72;

#pragma unroll
        for (int pt = 0; pt < 3; ++pt) {
            int pi = pt * 16 + pp;
            if (pi < 36) {
                int l = pi / 12;
                float2 so2 = *(const float2*)(sop + pi * 2);
                float fx = (l == 0) ? flx0 : (l == 1) ? flx1 : flx2;
                float fy = (l == 0) ? fly0 : (l == 1) ? fly1 : fly2;
                float bxf = (float)x + so2.x + fx;
                float byf = (float)y + so2.y + fy;
                float x0f = floorf(bxf), y0f = floorf(byf);
                float wx = bxf - x0f, wy = byf - y0f;
                float ax = 1.f - wx, ay = 1.f - wy;
                int x0 = (int)fminf(fmaxf(x0f, -2.f), 34.f);
                int y0 = (int)fminf(fmaxf(y0f, -2.f), 34.f);

                const unsigned short* pr = &pwlds[wav][pi * 12];
                uint2 pv0 = *(const uint2*)(pr);
                uint2 pv1 = *(const uint2*)(pr + 4);
                float a0 = bflo(pv0.x), a1 = bfhi(pv0.x), a2 = bflo(pv0.y);
                float a3 = bfhi(pv0.y), a4 = bflo(pv1.x), a5 = bfhi(pv1.x);
                float a6 = bflo(pv1.y), a7 = bfhi(pv1.y), a8 = bf2f(pr[8]);

                float bs0a, bs0b, bs1a, bs1b, bs2a, bs2b;
                {
                    float b0, b1, b2, b3;
                    b0 = a0 * ax; b1 = a0 * wx + a3 * ax; b2 = a3 * wx + a6 * ax; b3 = a6 * wx;
                    bs0a = selx ? b2 : b0; bs0b = selx ? b3 : b1;
                    b0 = a1 * ax; b1 = a1 * wx + a4 * ax; b2 = a4 * wx + a7 * ax; b3 = a7 * wx;
                    bs1a = selx ? b2 : b0; bs1b = selx ? b3 : b1;
                    b0 = a2 * ax; b1 = a2 * wx + a5 * ax; b2 = a5 * wx + a8 * ax; b3 = a8 * wx;
                    bs2a = selx ? b2 : b0; bs2b = selx ? b3 : b1;
                }
                float c00, c01, c10, c11;
                {
                    float c0 = bs0a * ay, c1 = bs0a * wy + bs1a * ay;
                    float c2 = bs1a * wy + bs2a * ay, c3 = bs2a * wy;
                    c00 = sely ? c2 : c0; c10 = sely ? c3 : c1;
                    c0 = bs0b * ay; c1 = bs0b * wy + bs1b * ay;
                    c2 = bs1b * wy + bs2b * ay; c3 = bs2b * wy;
                    c01 = sely ? c2 : c0; c11 = sely ? c3 : c1;
                }
                float cg[2][2] = {{c00, c01}, {c10, c11}};
                const int vbase = l * 1024;
#pragma unroll
                for (int sy = 0; sy < 2; ++sy) {
#pragma unroll
                    for (int sx = 0; sx < 2; ++sx) {
                        int dy = gdy + sy, dx = gdx + sx;
                        float pyf = y0f + (float)dy, pxf = x0f + (float)dx;
                        bool v = (pxf >= 0.f) && (pxf <= 31.f) && (pyf >= 0.f) && (pyf <= 31.f);
                        int px = min(max(x0 + dx, 0), 31);
                        int py = min(max(y0 + dy, 0), 31);
                        float c = cg[sy][sx] * (v ? 1.f : 0.f);
                        uint4 vv = *(const uint4*)(&vlds[(size_t)(vbase + py * 32 + px) * 8]);
                        acc[0] = fmaf(c, bflo(vv.x), acc[0]);
                        acc[1] = fmaf(c, bfhi(vv.x), acc[1]);
                        acc[2] = fmaf(c, bflo(vv.y), acc[2]);
                        acc[3] = fmaf(c, bfhi(vv.y), acc[3]);
                        acc[4] = fmaf(c, bflo(vv.z), acc[4]);
                        acc[5] = fmaf(c, bfhi(vv.z), acc[5]);
                        acc[6] = fmaf(c, bflo(vv.w), acc[6]);
                        acc[7] = fmaf(c, bfhi(vv.w), acc[7]);
                    }
                }
            }
        }

#pragma unroll
        for (int dd = 0; dd < 8; ++dd) {
#pragma unroll
            for (int off = 32; off; off >>= 1) acc[dd] += __shfl_xor(acc[dd], off);
        }
        if (lane == 0) {
            unsigned short* op = attn_pad + (size_t)((y + 1) * 34 + x + 1) * 192 + f * 64 + m * 8;
            ushort4 s0, s1;
            s0.x = f2bf(acc[0]); s0.y = f2bf(acc[1]); s0.z = f2bf(acc[2]); s0.w = f2bf(acc[3]);
            s1.x = f2bf(acc[4]); s1.y = f2bf(acc[5]); s1.z = f2bf(acc[6]); s1.w = f2bf(acc[7]);
            *(ushort4*)(op) = s0;
            *(ushort4*)(op + 4) = s1;
        }
    }
}

// ---------------------------------------------------------------------------
extern "C" void kernel_launch(void* const* d_in, const int* in_sizes, int n_in,
                              void* d_out, int out_size, void* d_ws, size_t ws_size,
                              hipStream_t stream) {
    const float* x      = (const float*)d_in[0];
    const float* flow_1 = (const float*)d_in[1];
    const float* flow_2 = (const float*)d_in[2];
    const float* flip_1 = (const float*)d_in[3];
    const float* flip_2 = (const float*)d_in[4];
    const float* vp0_w = (const float*)d_in[5];  const float* vp0_b = (const float*)d_in[6];
    const float* vp1_w = (const float*)d_in[7];  const float* vp1_b = (const float*)d_in[8];
    const float* so0_w = (const float*)d_in[9];  const float* so0_b = (const float*)d_in[10];
    const float* so1_w = (const float*)d_in[11]; const float* so1_b = (const float*)d_in[12];
    const float* so2_w = (const float*)d_in[13]; const float* so2_b = (const float*)d_in[14];
    const float* so3_w = (const float*)d_in[15]; const float* so3_b = (const float*)d_in[16];
    const float* aw0_w = (const float*)d_in[17]; const float* aw0_b = (const float*)d_in[18];
    const float* aw1_w = (const float*)d_in[19]; const float* aw1_b = (const float*)d_in[20];
    const float* aw2_w = (const float*)d_in[21]; const float* aw2_b = (const float*)d_in[22];
    const float* aw3_w = (const float*)d_in[23]; const float* aw3_b = (const float*)d_in[24];
    const float* op0_w = (const float*)d_in[25]; const float* op0_b = (const float*)d_in[26];
    const float* op1_w = (const float*)d_in[27]; const float* op1_b = (const float*)d_in[28];
    float* out = (float*)d_out;
    (void)ws_size; (void)in_sizes; (void)n_in; (void)out_size;

    // ---- workspace layout (identical to round-8) ----
    float* fws = (float*)d_ws;
    float* flow_cn2 = fws;
    float* flow_n2c = flow_cn2 + 2048;
    unsigned short* value_b = (unsigned short*)(flow_n2c + 2048);
    float* so_t     = (float*)(value_b + 196608);
    unsigned short* uws = (unsigned short*)(so_t + 1769472);
    unsigned short* x_pad     = uws;
    unsigned short* vp0h      = x_pad + 1156 * 192;
    unsigned short* extra_pad = vp0h + 1156 * 192;
    unsigned short* s1 = extra_pad + 1156 * 480;
    unsigned short* a1 = s1 + 1156 * 64;
    unsigned short* s2 = a1 + 1156 * 64;
    unsigned short* a2 = s2 + 1156 * 64;
    unsigned short* attn_pad = a2 + 1156 * 64;
    unsigned short* op0h     = attn_pad + 1156 * 192;
    unsigned short* aw_t = op0h + 1156 * 192;
    unsigned short* wgt  = aw_t + (size_t)3072 * 2592;

    // ---- 1. prep ----
    PrepP pp;
    pp.x = x; pp.f1 = flow_1; pp.f2 = flow_2; pp.ff1 = flip_1; pp.ff2 = flip_2;
    pp.fcn2 = flow_cn2; pp.fn2c = flow_n2c;
    pp.x_pad = x_pad; pp.extra_pad = extra_pad; pp.wgt = wgt;
    pp.wd[0]  = {vp0_w, 192, 192, 6,     0,    0};
    pp.wd[1]  = {vp1_w, 192, 192, 6,   648,   72};
    pp.wd[2]  = {so0_w,  64, 460, 15, 1296,  144};
    pp.wd[3]  = {aw0_w,  64, 460, 15, 1836,  204};
    pp.wd[4]  = {so1_w,  64,  64, 2,  2376,  264};
    pp.wd[5]  = {aw1_w,  64,  64, 2,  2448,  272};
    pp.wd[6]  = {so2_w,  64,  64, 2,  2520,  280};
    pp.wd[7]  = {aw2_w,  64,  64, 2,  2592,  288};
    pp.wd[8]  = {so3_w, 1728, 64, 2,  2664,  296};
    pp.wd[9]  = {aw3_w, 7776, 64, 2,  4608,  512};
    pp.wd[10] = {op0_w, 192, 192, 6, 13392, 1488};
    pp.wd[11] = {op1_w, 192, 192, 6, 14040, 1560};
    prep_k<<<3776, 256, 0, stream>>>(pp);

    const int BIG = 1 << 30;
    CDesc nul = {nullptr, nullptr, nullptr, nullptr, nullptr, 0, 0, 0, 0, 0, 0, BIG};

    // ---- 2. L1: vp0 + so0 + aw0 ----
    {
        CParam cp;
        cp.d[0] = {x_pad,     wgt + (size_t)0 * 512,    vp0_b, vp0h, nullptr, 192, 6,  192, 3, 192, 1, 12};
        cp.d[1] = {extra_pad, wgt + (size_t)1296 * 512, so0_b, s1,   nullptr, 480, 15, 64,  3, 64,  1, 4};
        cp.d[2] = {extra_pad, wgt + (size_t)1836 * 512, aw0_b, a1,   nullptr, 480, 15, 64,  3, 64,  1, 4};
        cp.d[3] = nul;
        conv_mfma_k<4, 16><<<dim3(20, 8), 256, 0, stream>>>(cp);
    }
    // ---- 3. L2': vp1 + fused so1->so2 + fused aw1->aw2 ----
    {
        L2FParam lp;
        lp.vp1 = {vp0h, wgt + (size_t)648 * 512, vp1_b, value_b, nullptr, 192, 6, 192, 2, 8, 0, 12};
        lp.so  = {s1, wgt + (size_t)2376 * 512, so1_b, wgt + (size_t)2520 * 512, so2_b, s2};
        lp.aw  = {a1, wgt + (size_t)2448 * 512, aw1_b, wgt + (size_t)2592 * 512, aw2_b, a2};
        l2f_k<<<dim3(14, 8), 256, 0, stream>>>(lp);
    }
    // ---- 4. L4: so3 + aw3 (inputs now s2 / a2) ----
    {
        CParam cp;
        cp.d[0] = {s2, wgt + (size_t)2664 * 512, so3_b, so_t, nullptr, 64, 2, 1728, 1, 576,  0, 27};
        cp.d[1] = {a2, wgt + (size_t)4608 * 512, aw3_b, aw_t, nullptr, 64, 2, 7776, 2, 2592, 0, 122};
        cp.d[2] = nul; cp.d[3] = nul;
        conv_mfma_k<8, 64><<<dim3(149, 4), 256, 0, stream>>>(cp);
    }

    // ---- 5. deformable attention ----
    deform_attn_k<<<768, 256, 0, stream>>>(value_b, so_t, aw_t,
                                           flow_1, flow_2, flip_1, flip_2,
                                           flow_cn2, flow_n2c, attn_pad);

    // ---- 6. op0 ----
    {
        CParam cp;
        cp.d[0] = {attn_pad, wgt + (size_t)13392 * 512, op0_b, op0h, nullptr, 192, 6, 192, 3, 192, 1, 12};
        cp.d[1] = nul; cp.d[2] = nul; cp.d[3] = nul;
        conv_mfma_k<4, 16><<<dim3(12, 8), 256, 0, stream>>>(cp);
    }
    // ---- 7. op1 + residual ----
    {
        CParam cp;
        cp.d[0] = {op0h, wgt + (size_t)14040 * 512, op1_b, out, x, 192, 6, 192, 0, 0, 0, 12};
        cp.d[1] = nul; cp.d[2] = nul; cp.d[3] = nul;
        conv_mfma_k<4, 16><<<dim3(12, 8), 256, 0, stream>>>(cp);
    }
}

// Round 11
// 281.909 us; speedup vs baseline: 2.8378x; 1.0082x over previous
//
#include <hip/hip_runtime.h>
#include <math.h>

#define HW 1024

typedef __attribute__((ext_vector_type(8))) short bf16x8;
typedef __attribute__((ext_vector_type(4))) float floatx4;

__device__ __forceinline__ unsigned short f2bf(float f) {
    unsigned u = __float_as_uint(f);
    u += 0x7FFF + ((u >> 16) & 1);
    return (unsigned short)(u >> 16);
}
__device__ __forceinline__ float bf2f(unsigned short u) {
    return __uint_as_float(((unsigned)u) << 16);
}
__device__ __forceinline__ float bflo(unsigned u) { return __uint_as_float(u << 16); }
__device__ __forceinline__ float bfhi(unsigned u) { return __uint_as_float(u & 0xffff0000u); }

// ---------------------------------------------------------------------------
// Bilinear sample, zero padding, absolute pixel coords (matches reference).
// ---------------------------------------------------------------------------
__device__ __forceinline__ float bilin32(const float* __restrict__ img, float px, float py) {
    float x0f = floorf(px), y0f = floorf(py);
    float wx = px - x0f, wy = py - y0f;
    bool vx0 = (x0f >= 0.f) && (x0f <= 31.f);
    bool vx1 = (x0f >= -1.f) && (x0f <= 30.f);
    bool vy0 = (y0f >= 0.f) && (y0f <= 31.f);
    bool vy1 = (y0f >= -1.f) && (y0f <= 30.f);
    int ix0 = (int)fminf(fmaxf(x0f, 0.f), 31.f);
    int iy0 = (int)fminf(fmaxf(y0f, 0.f), 31.f);
    int ix1 = (int)fminf(fmaxf(x0f + 1.f, 0.f), 31.f);
    int iy1 = (int)fminf(fmaxf(y0f + 1.f, 0.f), 31.f);
    float w00 = (1.f - wx) * (1.f - wy) * ((vx0 && vy0) ? 1.f : 0.f);
    float w01 = wx * (1.f - wy) * ((vx1 && vy0) ? 1.f : 0.f);
    float w10 = (1.f - wx) * wy * ((vx0 && vy1) ? 1.f : 0.f);
    float w11 = wx * wy * ((vx1 && vy1) ? 1.f : 0.f);
    return w00 * img[iy0 * 32 + ix0] + w01 * img[iy0 * 32 + ix1] +
           w10 * img[iy1 * 32 + ix0] + w11 * img[iy1 * 32 + ix1];
}

__device__ __forceinline__ float2 comp_flow(const float* __restrict__ fa,
                                            const float* __restrict__ fb, int pix) {
    int y = pix >> 5, x = pix & 31;
    float fx = fa[pix], fy = fa[HW + pix];
    float px = (float)x + fx, py = (float)y + fy;
    float2 r;
    r.x = fx + bilin32(fb, px, py);
    r.y = fy + bilin32(fb + HW, px, py);
    return r;
}

// ---------------------------------------------------------------------------
// Weight transform tile: one (co16, cb) -> 9 fragment blocks of 512 bf16.
// LDS needs 16*288 floats = 18432 B of smraw.
// ---------------------------------------------------------------------------
struct WD { const float* src; int cout, Cin, nCb, wbase, beg; };

__device__ __forceinline__ void wxform_tile(const WD w, int local,
                                            unsigned short* __restrict__ wgt, char* smraw) {
    float* wlds = (float*)smraw;
    const int tid = threadIdx.x;
    int co16 = local / w.nCb, cb = local - co16 * w.nCb;
    int cr0 = co16 * 16, ci0 = cb * 32;
    for (int i = tid; i < 16 * 288; i += 256) {
        int cr = i / 288, o = i - cr * 288;
        int crg = cr0 + cr, ci = ci0 + o / 9;
        float v = (crg < w.cout && ci < w.Cin)
            ? w.src[((size_t)crg * w.Cin + ci0) * 9 + o] : 0.f;
        wlds[i] = v;
    }
    __syncthreads();
    for (int e = tid; e < 9 * 512; e += 256) {
        int t = e >> 9, idx = e & 511;
        int j = idx & 7, lane = idx >> 3, q = lane >> 4, mm = lane & 15;
        wgt[((size_t)w.wbase + ((size_t)co16 * 9 + t) * w.nCb + cb) * 512 + idx] =
            f2bf(wlds[mm * 288 + (q * 8 + j) * 9 + t]);
    }
}

// ---------------------------------------------------------------------------
// Prep kernel: sections by blockIdx.x (grid 968).
//  [0,192)    xpad: x -> x_pad bf16 [34*34][192]
//  [192,672)  build_extra, 4 channels/thread (shared bilinear coords)
//  [672,688)  flow_cn2 / flow_n2c fp32
//  [688,704)  border zeroing of the 9 padded bf16 buffers
//  [704,968)  wxform for vp0, vp1, so0, aw0 only (rest rides in conv launches)
// ---------------------------------------------------------------------------
struct PrepP {
    const float *x, *f1, *f2, *ff1, *ff2;
    float *fcn2, *fn2c;
    unsigned short *x_pad, *extra_pad, *wgt;
    WD wd[4];
};

__global__ __launch_bounds__(256) void prep_k(PrepP P) {
    __shared__ __align__(16) char sm[16 * 288 * 4];
    const int b = blockIdx.x, tid = threadIdx.x;
    if (b < 192) {
        int idx = b * 256 + tid;                 // < 1024*48
        int pix = idx / 48, c4 = idx - pix * 48;
        int y = pix >> 5, xx = pix & 31;
        int c0 = c4 * 4;
        ushort4 s;
        s.x = f2bf(P.x[(size_t)(c0 + 0) * HW + pix]);
        s.y = f2bf(P.x[(size_t)(c0 + 1) * HW + pix]);
        s.z = f2bf(P.x[(size_t)(c0 + 2) * HW + pix]);
        s.w = f2bf(P.x[(size_t)(c0 + 3) * HW + pix]);
        *(ushort4*)(&P.x_pad[(size_t)((y + 1) * 34 + xx + 1) * 192 + c0]) = s;
    } else if (b < 672) {
        int idx = (b - 192) * 256 + tid;         // < 1024*120
        int pix = idx / 120, c4 = idx - pix * 120;
        int y = pix >> 5, xx = pix & 31;
        int c0 = c4 * 4;
        float va[4];
        if (c0 < 64) {
#pragma unroll
            for (int k = 0; k < 4; ++k) va[k] = P.x[(size_t)(c0 + k) * HW + pix];
        } else if (c0 < 448) {
            int grp = (c0 - 64) >> 6;
            int c = (c0 - 64) & 63;
            const float* src; float fx, fy;
            if (grp == 0)      { src = P.x + 64 * HW;  fx = P.f1[pix];  fy = P.f1[HW + pix]; }
            else if (grp == 1) { src = P.x + 128 * HW; float2 r = comp_flow(P.f1, P.f2, pix);  fx = r.x; fy = r.y; }
            else if (grp == 2) { src = P.x;            fx = P.ff1[pix]; fy = P.ff1[HW + pix]; }
            else if (grp == 3) { src = P.x + 128 * HW; fx = P.f2[pix];  fy = P.f2[HW + pix]; }
            else if (grp == 4) { src = P.x + 64 * HW;  fx = P.ff2[pix]; fy = P.ff2[HW + pix]; }
            else               { src = P.x;            float2 r = comp_flow(P.ff2, P.ff1, pix); fx = r.x; fy = r.y; }
            float px = (float)xx + fx, py = (float)y + fy;
            float x0f = floorf(px), y0f = floorf(py);
            float wx = px - x0f, wy = py - y0f;
            bool vx0 = (x0f >= 0.f) && (x0f <= 31.f);
            bool vx1 = (x0f >= -1.f) && (x0f <= 30.f);
            bool vy0 = (y0f >= 0.f) && (y0f <= 31.f);
            bool vy1 = (y0f >= -1.f) && (y0f <= 30.f);
            int ix0 = (int)fminf(fmaxf(x0f, 0.f), 31.f);
            int iy0 = (int)fminf(fmaxf(y0f, 0.f), 31.f);
            int ix1 = (int)fminf(fmaxf(x0f + 1.f, 0.f), 31.f);
            int iy1 = (int)fminf(fmaxf(y0f + 1.f, 0.f), 31.f);
            float w00 = (1.f - wx) * (1.f - wy) * ((vx0 && vy0) ? 1.f : 0.f);
            float w01 = wx * (1.f - wy) * ((vx1 && vy0) ? 1.f : 0.f);
            float w10 = (1.f - wx) * wy * ((vx0 && vy1) ? 1.f : 0.f);
            float w11 = wx * wy * ((vx1 && vy1) ? 1.f : 0.f);
            int p00 = iy0 * 32 + ix0, p01 = iy0 * 32 + ix1;
            int p10 = iy1 * 32 + ix0, p11 = iy1 * 32 + ix1;
            const float* im = src + (size_t)c * HW;
#pragma unroll
            for (int k = 0; k < 4; ++k) {
                va[k] = w00 * im[p00] + w01 * im[p01] + w10 * im[p10] + w11 * im[p11];
                im += HW;
            }
        } else {
#pragma unroll
            for (int k = 0; k < 4; ++k) {
                int ch = c0 + k;
                float v = 0.f;
                if (ch < 460) {
                    int fc = ch - 448;
                    int which = fc >> 1, comp = fc & 1;
                    if (which == 0)      v = P.f1[comp * HW + pix];
                    else if (which == 1) { float2 r = comp_flow(P.f1, P.f2, pix);  v = comp ? r.y : r.x; }
                    else if (which == 2) v = P.ff1[comp * HW + pix];
                    else if (which == 3) v = P.f2[comp * HW + pix];
                    else if (which == 4) v = P.ff2[comp * HW + pix];
                    else                 { float2 r = comp_flow(P.ff2, P.ff1, pix); v = comp ? r.y : r.x; }
                }
                va[k] = v;
            }
        }
        ushort4 s;
        s.x = f2bf(va[0]); s.y = f2bf(va[1]); s.z = f2bf(va[2]); s.w = f2bf(va[3]);
        *(ushort4*)(&P.extra_pad[(size_t)((y + 1) * 34 + xx + 1) * 480 + c0]) = s;
    } else if (b < 688) {
        int idx = (b - 672) * 256 + tid;
        if (idx < 1024) {
            float2 r = comp_flow(P.f1, P.f2, idx);
            P.fcn2[idx] = r.x; P.fcn2[HW + idx] = r.y;
        } else if (idx < 2048) {
            int pix = idx - 1024;
            float2 r = comp_flow(P.ff2, P.ff1, pix);
            P.fn2c[pix] = r.x; P.fn2c[HW + pix] = r.y;
        }
    } else if (b < 704) {
        const int chans[9] = {192, 192, 480, 64, 64, 64, 64, 192, 192};
        size_t offs[9]; size_t a = 0;
        for (int i = 0; i < 9; ++i) { offs[i] = a; a += (size_t)1156 * chans[i]; }
        int bb = b - 688;
        for (int item = bb; item < 9 * 132; item += 16) {
            int buf = item / 132, i = item - buf * 132;
            int py, px;
            if (i < 34) { py = 0; px = i; }
            else if (i < 68) { py = 33; px = i - 34; }
            else { int j = i - 68; py = 1 + (j >> 1); px = (j & 1) ? 33 : 0; }
            int C = chans[buf];
            unsigned short* p = P.x_pad + offs[buf] + (size_t)(py * 34 + px) * C;
            for (int c = tid; c < C; c += 256) p[c] = 0;
        }
    } else {
        int blk = b - 704;                       // < 264
        int di = 0;
        while (di < 3 && blk >= P.wd[di + 1].beg) ++di;
        wxform_tile(P.wd[di], blk - P.wd[di].beg, P.wgt, sm);
    }
}

// ---------------------------------------------------------------------------
// MFMA 3x3 conv tile, register-prefetch double-buffered.
// ---------------------------------------------------------------------------
struct CDesc {
    const unsigned short* in;
    const unsigned short* wgt;
    const float* bias;
    void* out;
    const float* residual;
    int Cpad, nCb, Cout, mode, cmod, relu, Mblocks;
};
struct CParam {
    CDesc d[4];
    WD rwd[4];          // rider wxform descriptors
    int rbeg[5];        // slot ranges; rbeg[nr] = total slots
    int nr;             // rider count (0 = none)
    int ride_bx0;       // bx >= this -> rider block
    unsigned short* wgt;
};

template<int PIXROWS, int COBLK>
__device__ __forceinline__ void conv_tile(const CDesc d, int bx, int by, char* smraw) {
    constexpr int TROWS = PIXROWS + 2;
    constexpr int TC = TROWS * 34 * 4;
    constexpr int ITRIPS = (TC + 255) / 256;
    constexpr int NTY = PIXROWS / 4;
    constexpr int NACC = NTY * 2;
    constexpr int MT = COBLK / 16;
    constexpr int WN = MT * 9 * 64;
    constexpr int WTRIPS = (WN + 255) / 256;
    unsigned short* blds = (unsigned short*)smraw;
    unsigned short* wlds = (unsigned short*)(smraw + TROWS * 34 * 40 * 2);

    const int tid = threadIdx.x;
    const int w = tid >> 6, lane = tid & 63;
    const int lq = lane >> 4, ln = lane & 15;
    const int co0 = bx * COBLK;
    const int y0 = by * PIXROWS;
    const unsigned short* __restrict__ in = d.in;
    const unsigned short* __restrict__ wg = d.wgt;
    const int Cpad = d.Cpad, nCb = d.nCb;

    floatx4 acc[MT][NACC];
#pragma unroll
    for (int mt = 0; mt < MT; ++mt)
#pragma unroll
        for (int nt = 0; nt < NACC; ++nt)
            acc[mt][nt] = (floatx4){0.f, 0.f, 0.f, 0.f};

    bf16x8 ireg[ITRIPS];
    bf16x8 wreg[WTRIPS];

    auto load_regs = [&](int cb) {
        const int ci0 = cb << 5;
#pragma unroll
        for (int k = 0; k < ITRIPS; ++k) {
            int i = tid + k * 256;
            if (i < TC) {
                int r = i / 136, rem = i - r * 136, c = rem >> 2, g = rem & 3;
                ireg[k] = *(const bf16x8*)(in + (size_t)((y0 + r) * 34 + c) * Cpad + ci0 + g * 8);
            }
        }
#pragma unroll
        for (int k = 0; k < WTRIPS; ++k) {
            int i = tid + k * 256;
            if (i < WN) {
                int chunk = i >> 6, l16 = i & 63;
                int mt = chunk / 9, t = chunk - mt * 9;
                wreg[k] = *(const bf16x8*)(wg + ((size_t)(((co0 >> 4) + mt) * 9 + t) * nCb + cb) * 512 + l16 * 8);
            }
        }
    };

    load_regs(0);

    for (int cb = 0; cb < nCb; ++cb) {
        __syncthreads();
#pragma unroll
        for (int k = 0; k < ITRIPS; ++k) {
            int i = tid + k * 256;
            if (i < TC) {
                int r = i / 136, rem = i - r * 136, c = rem >> 2, g = rem & 3;
                *(bf16x8*)(&blds[(r * 34 + c) * 40 + g * 8]) = ireg[k];
            }
        }
#pragma unroll
        for (int k = 0; k < WTRIPS; ++k) {
            int i = tid + k * 256;
            if (i < WN) {
                int chunk = i >> 6, l16 = i & 63;
                *(bf16x8*)(&wlds[chunk * 512 + l16 * 8]) = wreg[k];
            }
        }
        __syncthreads();
        if (cb + 1 < nCb) load_regs(cb + 1);
        for (int t = 0; t < 9; ++t) {
            const int dy = t / 3, dx = t - dy * 3;
            bf16x8 bfr[NACC];
#pragma unroll
            for (int ty = 0; ty < NTY; ++ty)
#pragma unroll
                for (int tx = 0; tx < 2; ++tx) {
                    int yy = w * NTY + ty + dy;
                    int xx = tx * 16 + ln + dx;
                    bfr[ty * 2 + tx] = *(const bf16x8*)(&blds[(yy * 34 + xx) * 40 + lq * 8]);
                }
#pragma unroll
            for (int mt = 0; mt < MT; ++mt) {
                bf16x8 afr = *(const bf16x8*)(&wlds[(mt * 9 + t) * 512 + lane * 8]);
#pragma unroll
                for (int nt = 0; nt < NACC; ++nt)
                    acc[mt][nt] = __builtin_amdgcn_mfma_f32_16x16x32_bf16(afr, bfr[nt], acc[mt][nt], 0, 0, 0);
            }
        }
    }

#pragma unroll
    for (int mt = 0; mt < MT; ++mt) {
        const int co = co0 + mt * 16 + lq * 4;
        if (co >= d.Cout) continue;
        float bv[4];
#pragma unroll
        for (int r = 0; r < 4; ++r) bv[r] = d.bias[co + r];
#pragma unroll
        for (int nt = 0; nt < NACC; ++nt) {
            const int ty = nt >> 1, tx = nt & 1;
            const int pix = by * (PIXROWS * 32) + (w * NTY + ty) * 32 + tx * 16 + ln;
            float v[4];
#pragma unroll
            for (int r = 0; r < 4; ++r) {
                float vv = acc[mt][nt][r] + bv[r];
                if (d.relu) vv = (vv >= 0.f) ? vv : 0.1f * vv;
                v[r] = vv;
            }
            if (d.mode == 0) {
                float* o = (float*)d.out;
#pragma unroll
                for (int r = 0; r < 4; ++r) {
                    float vv = v[r];
                    if (d.residual) vv += d.residual[(size_t)(co + r) * HW + pix];
                    o[(size_t)(co + r) * HW + pix] = vv;
                }
            } else if (d.mode == 1) {
                int fq = co / d.cmod, cc = co - fq * d.cmod;
                *(float4*)((float*)d.out + ((size_t)fq * HW + pix) * d.cmod + cc) =
                    make_float4(v[0], v[1], v[2], v[3]);
            } else if (d.mode == 2) {
                int fq = co / d.cmod, cc = co - fq * d.cmod;
                ushort4 s4;
                s4.x = f2bf(v[0]); s4.y = f2bf(v[1]); s4.z = f2bf(v[2]); s4.w = f2bf(v[3]);
                *(ushort4*)((unsigned short*)d.out + ((size_t)fq * HW + pix) * d.cmod + cc) = s4;
            } else {
                int yy = (pix >> 5) + 1, xx = (pix & 31) + 1;
                ushort4 s4;
                s4.x = f2bf(v[0]); s4.y = f2bf(v[1]); s4.z = f2bf(v[2]); s4.w = f2bf(v[3]);
                *(ushort4*)((unsigned short*)d.out + (size_t)(yy * 34 + xx) * d.cmod + co) = s4;
            }
        }
    }
}

// Multi-descriptor conv dispatch with optional wxform riders on extra bx.
template<int PIXROWS, int COBLK>
__global__ __launch_bounds__(256) void conv_mfma_k(CParam P) {
    constexpr int TROWS = PIXROWS + 2;
    constexpr int MT = COBLK / 16;
    constexpr int SMB = TROWS * 34 * 40 * 2 + MT * 9 * 512 * 2;
    __shared__ __align__(16) char sm[(SMB > 18432) ? SMB : 18432];
    int bx = blockIdx.x;
    if (P.nr > 0 && bx >= P.ride_bx0) {
        int slot = (bx - P.ride_bx0) * gridDim.y + blockIdx.y;
        if (slot >= P.rbeg[P.nr]) return;
        int di = 0;
        while (di + 1 < P.nr && slot >= P.rbeg[di + 1]) ++di;
        wxform_tile(P.rwd[di], slot - P.rbeg[di], P.wgt, sm);
        return;
    }
    int di = 0;
    while (bx >= P.d[di].Mblocks) { bx -= P.d[di].Mblocks; ++di; }
    conv_tile<PIXROWS, COBLK>(P.d[di], bx, blockIdx.y, sm);
}

// ---------------------------------------------------------------------------
// Deformable attention: LDS value + patch-convolution gathers + software
// pipelining (so-offset loads hoisted; next q's logits prefetched into regs
// before the gather phase).
// ---------------------------------------------------------------------------
__global__ __launch_bounds__(256) void deform_attn_k(
    const unsigned short* __restrict__ value_b, const float* __restrict__ so_t,
    const unsigned short* __restrict__ aw_t,
    const float* __restrict__ flow_1, const float* __restrict__ flow_2,
    const float* __restrict__ flip_flow_1, const float* __restrict__ flip_flow_2,
    const float* __restrict__ flow_cn2, const float* __restrict__ flow_n2c,
    unsigned short* __restrict__ attn_pad)
{
    __shared__ unsigned short vlds[24576];
    __shared__ unsigned short pwlds[4][432];
    const int tid = threadIdx.x;
    const int wav = tid >> 6, lane = tid & 63;
    const int m = blockIdx.x & 7, qc = blockIdx.x >> 3;

    for (int i = tid; i < 3072; i += 256) {
        int l = i >> 10, p = i & 1023;
        *(bf16x8*)(&vlds[(size_t)i * 8]) =
            *(const bf16x8*)(value_b + ((size_t)((l * 8 + m) * 1024) + p) * 8);
    }
    __syncthreads();

    const int pp = lane & 15, gq = lane >> 4;
    const int gdy = (gq >> 1) * 2 - 1;
    const int gdx = (gq & 1) * 2 - 1;
    const bool selx = (gq & 1);
    const bool sely = (gq >> 1);

    // preload logits for r=0
    float av[6];
    {
        const unsigned short* awp = aw_t + (size_t)(qc * 32 + wav) * 2592 + m * 324;
#pragma unroll
        for (int it = 0; it < 6; ++it) {
            int j = lane + it * 64;
            av[it] = (j < 324) ? bf2f(awp[j]) : -1e30f;
        }
    }

    for (int r = 0; r < 8; ++r) {
        const int q = qc * 32 + r * 4 + wav;
        const int f = q >> 10, pix = q & 1023;
        const int y = pix >> 5, x = pix & 31;

        // hoist so-offset loads (latency hides under softmax)
        const float* sop = so_t + (size_t)q * 576 + m * 72;
        float2 so2r[3];
#pragma unroll
        for (int pt = 0; pt < 3; ++pt) {
            int pi = pt * 16 + pp;
            if (pi < 36) so2r[pt] = *(const float2*)(sop + pi * 2);
            else { so2r[pt].x = 0.f; so2r[pt].y = 0.f; }
        }

        float flx0 = 0.f, fly0 = 0.f, flx1 = 0.f, fly1 = 0.f, flx2 = 0.f, fly2 = 0.f;
        if (f == 0) {
            flx1 = flow_1[pix];      fly1 = flow_1[HW + pix];
            flx2 = flow_cn2[pix];    fly2 = flow_cn2[HW + pix];
        } else if (f == 1) {
            flx0 = flip_flow_1[pix]; fly0 = flip_flow_1[HW + pix];
            flx2 = flow_2[pix];      fly2 = flow_2[HW + pix];
        } else {
            flx0 = flow_n2c[pix];    fly0 = flow_n2c[HW + pix];
            flx1 = flip_flow_2[pix]; fly1 = flip_flow_2[HW + pix];
        }

        // ---- softmax over 324 logits (already in av) ----
        float vmax = -1e30f;
#pragma unroll
        for (int it = 0; it < 6; ++it) vmax = fmaxf(vmax, av[it]);
#pragma unroll
        for (int off = 32; off; off >>= 1) vmax = fmaxf(vmax, __shfl_xor(vmax, off));
        float ssum = 0.f;
#pragma unroll
        for (int it = 0; it < 6; ++it) {
            int j = lane + it * 64;
            float e = (j < 324) ? __expf(av[it] - vmax) : 0.f;
            av[it] = e;
            ssum += e;
        }
#pragma unroll
        for (int off = 32; off; off >>= 1) ssum += __shfl_xor(ssum, off);
        const float inv = 1.f / ssum;

#pragma unroll
        for (int it = 0; it < 6; ++it) {
            int j = lane + it * 64;
            if (j < 324) {
                int pi = j / 9, k = j - pi * 9;
                pwlds[wav][pi * 12 + k] = f2bf(av[it] * inv);
            }
        }

        // prefetch next q's logits (in flight during the gather phase)
        float avn[6];
        if (r < 7) {
            const unsigned short* awn = aw_t + (size_t)(q + 4) * 2592 + m * 324;
#pragma unroll
            for (int it = 0; it < 6; ++it) {
                int j = lane + it * 64;
                avn[it] = (j < 324) ? bf2f(awn[j]) : -1e30f;
            }
        }

        // ---- patch-convolution gather ----
        float acc[8];
#pragma unroll
        for (int dd = 0; dd < 8; ++dd) acc[dd] = 0.f;

#pragma unroll
        for (int pt = 0; pt < 3; ++pt) {
            int pi = pt * 16 + pp;
            if (pi < 36) {
                int l = pi / 12;
                float2 so2 = so2r[pt];
                float fx = (l == 0) ? flx0 : (l == 1) ? flx1 : flx2;
                float fy = (l == 0) ? fly0 : (l == 1) ? fly1 : fly2;
                float bxf = (float)x + so2.x + fx;
                float byf = (float)y + so2.y + fy;
                float x0f = floorf(bxf), y0f = floorf(byf);
                float wx = bxf - x0f, wy = byf - y0f;
                float ax = 1.f - wx, ay = 1.f - wy;
                int x0 = (int)fminf(fmaxf(x0f, -2.f), 34.f);
                int y0 = (int)fminf(fmaxf(y0f, -2.f), 34.f);

                const unsigned short* pr = &pwlds[wav][pi * 12];
                uint2 pv0 = *(const uint2*)(pr);
                uint2 pv1 = *(const uint2*)(pr + 4);
                float a0 = bflo(pv0.x), a1 = bfhi(pv0.x), a2 = bflo(pv0.y);
                float a3 = bfhi(pv0.y), a4 = bflo(pv1.x), a5 = bfhi(pv1.x);
                float a6 = bflo(pv1.y), a7 = bfhi(pv1.y), a8 = bf2f(pr[8]);

                float bs0a, bs0b, bs1a, bs1b, bs2a, bs2b;
                {
                    float b0, b1, b2, b3;
                    b0 = a0 * ax; b1 = a0 * wx + a3 * ax; b2 = a3 * wx + a6 * ax; b3 = a6 * wx;
                    bs0a = selx ? b2 : b0; bs0b = selx ? b3 : b1;
                    b0 = a1 * ax; b1 = a1 * wx + a4 * ax; b2 = a4 * wx + a7 * ax; b3 = a7 * wx;
                    bs1a = selx ? b2 : b0; bs1b = selx ? b3 : b1;
                    b0 = a2 * ax; b1 = a2 * wx + a5 * ax; b2 = a5 * wx + a8 * ax; b3 = a8 * wx;
                    bs2a = selx ? b2 : b0; bs2b = selx ? b3 : b1;
                }
                float c00, c01, c10, c11;
                {
                    float c0 = bs0a * ay, c1 = bs0a * wy + bs1a * ay;
                    float c2 = bs1a * wy + bs2a * ay, c3 = bs2a * wy;
                    c00 = sely ? c2 : c0; c10 = sely ? c3 : c1;
                    c0 = bs0b * ay; c1 = bs0b * wy + bs1b * ay;
                    c2 = bs1b * wy + bs2b * ay; c3 = bs2b * wy;
                    c01 = sely ? c2 : c0; c11 = sely ? c3 : c1;
                }
                float cg[2][2] = {{c00, c01}, {c10, c11}};
                const int vbase = l * 1024;
#pragma unroll
                for (int sy = 0; sy < 2; ++sy) {
#pragma unroll
                    for (int sx = 0; sx < 2; ++sx) {
                        int dy = gdy + sy, dx = gdx + sx;
                        float pyf = y0f + (float)dy, pxf = x0f + (float)dx;
                        bool v = (pxf >= 0.f) && (pxf <= 31.f) && (pyf >= 0.f) && (pyf <= 31.f);
                        int px = min(max(x0 + dx, 0), 31);
                        int py = min(max(y0 + dy, 0), 31);
                        float c = cg[sy][sx] * (v ? 1.f : 0.f);
                        uint4 vv = *(const uint4*)(&vlds[(size_t)(vbase + py * 32 + px) * 8]);
                        acc[0] = fmaf(c, bflo(vv.x), acc[0]);
                        acc[1] = fmaf(c, bfhi(vv.x), acc[1]);
                        acc[2] = fmaf(c, bflo(vv.y), acc[2]);
                        acc[3] = fmaf(c, bfhi(vv.y), acc[3]);
                        acc[4] = fmaf(c, bflo(vv.z), acc[4]);
                        acc[5] = fmaf(c, bfhi(vv.z), acc[5]);
                        acc[6] = fmaf(c, bflo(vv.w), acc[6]);
                        acc[7] = fmaf(c, bfhi(vv.w), acc[7]);
                    }
                }
            }
        }

#pragma unroll
        for (int dd = 0; dd < 8; ++dd) {
#pragma unroll
            for (int off = 32; off; off >>= 1) acc[dd] += __shfl_xor(acc[dd], off);
        }
        if (lane == 0) {
            unsigned short* op = attn_pad + (size_t)((y + 1) * 34 + x + 1) * 192 + f * 64 + m * 8;
            ushort4 s0, s1;
            s0.x = f2bf(acc[0]); s0.y = f2bf(acc[1]); s0.z = f2bf(acc[2]); s0.w = f2bf(acc[3]);
            s1.x = f2bf(acc[4]); s1.y = f2bf(acc[5]); s1.z = f2bf(acc[6]); s1.w = f2bf(acc[7]);
            *(ushort4*)(op) = s0;
            *(ushort4*)(op + 4) = s1;
        }
        if (r < 7) {
#pragma unroll
            for (int it = 0; it < 6; ++it) av[it] = avn[it];
        }
    }
}

// ---------------------------------------------------------------------------
extern "C" void kernel_launch(void* const* d_in, const int* in_sizes, int n_in,
                              void* d_out, int out_size, void* d_ws, size_t ws_size,
                              hipStream_t stream) {
    const float* x      = (const float*)d_in[0];
    const float* flow_1 = (const float*)d_in[1];
    const float* flow_2 = (const float*)d_in[2];
    const float* flip_1 = (const float*)d_in[3];
    const float* flip_2 = (const float*)d_in[4];
    const float* vp0_w = (const float*)d_in[5];  const float* vp0_b = (const float*)d_in[6];
    const float* vp1_w = (const float*)d_in[7];  const float* vp1_b = (const float*)d_in[8];
    const float* so0_w = (const float*)d_in[9];  const float* so0_b = (const float*)d_in[10];
    const float* so1_w = (const float*)d_in[11]; const float* so1_b = (const float*)d_in[12];
    const float* so2_w = (const float*)d_in[13]; const float* so2_b = (const float*)d_in[14];
    const float* so3_w = (const float*)d_in[15]; const float* so3_b = (const float*)d_in[16];
    const float* aw0_w = (const float*)d_in[17]; const float* aw0_b = (const float*)d_in[18];
    const float* aw1_w = (const float*)d_in[19]; const float* aw1_b = (const float*)d_in[20];
    const float* aw2_w = (const float*)d_in[21]; const float* aw2_b = (const float*)d_in[22];
    const float* aw3_w = (const float*)d_in[23]; const float* aw3_b = (const float*)d_in[24];
    const float* op0_w = (const float*)d_in[25]; const float* op0_b = (const float*)d_in[26];
    const float* op1_w = (const float*)d_in[27]; const float* op1_b = (const float*)d_in[28];
    float* out = (float*)d_out;
    (void)ws_size; (void)in_sizes; (void)n_in; (void)out_size;

    // ---- workspace layout (round-8) ----
    float* fws = (float*)d_ws;
    float* flow_cn2 = fws;
    float* flow_n2c = flow_cn2 + 2048;
    unsigned short* value_b = (unsigned short*)(flow_n2c + 2048);
    float* so_t     = (float*)(value_b + 196608);
    unsigned short* uws = (unsigned short*)(so_t + 1769472);
    unsigned short* x_pad     = uws;
    unsigned short* vp0h      = x_pad + 1156 * 192;
    unsigned short* extra_pad = vp0h + 1156 * 192;
    unsigned short* s1 = extra_pad + 1156 * 480;
    unsigned short* a1 = s1 + 1156 * 64;
    unsigned short* s2 = a1 + 1156 * 64;
    unsigned short* a2 = s2 + 1156 * 64;
    unsigned short* attn_pad = a2 + 1156 * 64;
    unsigned short* op0h     = attn_pad + 1156 * 192;
    unsigned short* aw_t = op0h + 1156 * 192;
    unsigned short* wgt  = aw_t + (size_t)3072 * 2592;

    // ---- 1. prep (wxform only for vp0, vp1, so0, aw0) ----
    PrepP pp;
    pp.x = x; pp.f1 = flow_1; pp.f2 = flow_2; pp.ff1 = flip_1; pp.ff2 = flip_2;
    pp.fcn2 = flow_cn2; pp.fn2c = flow_n2c;
    pp.x_pad = x_pad; pp.extra_pad = extra_pad; pp.wgt = wgt;
    pp.wd[0] = {vp0_w, 192, 192, 6,     0,   0};
    pp.wd[1] = {vp1_w, 192, 192, 6,   648,  72};
    pp.wd[2] = {so0_w,  64, 460, 15, 1296, 144};
    pp.wd[3] = {aw0_w,  64, 460, 15, 1836, 204};
    prep_k<<<968, 256, 0, stream>>>(pp);

    const int BIG = 1 << 30;
    CDesc nul = {nullptr, nullptr, nullptr, nullptr, nullptr, 0, 0, 0, 0, 0, 0, BIG};
    WD wnul = {nullptr, 0, 0, 1, 0, 0};

    // ---- 2. L1: vp0 + so0 + aw0  (+riders: wxform so1,aw1,so2,aw2) ----
    {
        CParam cp;
        cp.d[0] = {x_pad,     wgt + (size_t)0 * 512,    vp0_b, vp0h, nullptr, 192, 6,  192, 3, 192, 1, 12};
        cp.d[1] = {extra_pad, wgt + (size_t)1296 * 512, so0_b, s1,   nullptr, 480, 15, 64,  3, 64,  1, 4};
        cp.d[2] = {extra_pad, wgt + (size_t)1836 * 512, aw0_b, a1,   nullptr, 480, 15, 64,  3, 64,  1, 4};
        cp.d[3] = nul;
        cp.rwd[0] = {so1_w, 64, 64, 2, 2376, 0};
        cp.rwd[1] = {aw1_w, 64, 64, 2, 2448, 0};
        cp.rwd[2] = {so2_w, 64, 64, 2, 2520, 0};
        cp.rwd[3] = {aw2_w, 64, 64, 2, 2592, 0};
        cp.rbeg[0] = 0; cp.rbeg[1] = 8; cp.rbeg[2] = 16; cp.rbeg[3] = 24; cp.rbeg[4] = 32;
        cp.nr = 4; cp.ride_bx0 = 20; cp.wgt = wgt;
        conv_mfma_k<4, 16><<<dim3(24, 8), 256, 0, stream>>>(cp);
    }
    // ---- 3. L2: vp1 + so1 + aw1  (+riders: wxform so3, aw3) ----
    {
        CParam cp;
        cp.d[0] = {vp0h, wgt + (size_t)648 * 512,  vp1_b, value_b, nullptr, 192, 6, 192, 2, 8,  0, 12};
        cp.d[1] = {s1,   wgt + (size_t)2376 * 512, so1_b, s2,      nullptr, 64,  2, 64,  3, 64, 1, 4};
        cp.d[2] = {a1,   wgt + (size_t)2448 * 512, aw1_b, a2,      nullptr, 64,  2, 64,  3, 64, 1, 4};
        cp.d[3] = nul;
        cp.rwd[0] = {so3_w, 1728, 64, 2, 2664, 0};
        cp.rwd[1] = {aw3_w, 7776, 64, 2, 4608, 0};
        cp.rwd[2] = wnul; cp.rwd[3] = wnul;
        cp.rbeg[0] = 0; cp.rbeg[1] = 216; cp.rbeg[2] = 1188; cp.rbeg[3] = 1188; cp.rbeg[4] = 1188;
        cp.nr = 2; cp.ride_bx0 = 20; cp.wgt = wgt;
        conv_mfma_k<4, 16><<<dim3(169, 8), 256, 0, stream>>>(cp);
    }
    // ---- 4. L3: so2 + aw2  (+riders: wxform op0, op1) ----
    {
        CParam cp;
        cp.d[0] = {s2, wgt + (size_t)2520 * 512, so2_b, s1, nullptr, 64, 2, 64, 3, 64, 1, 4};
        cp.d[1] = {a2, wgt + (size_t)2592 * 512, aw2_b, a1, nullptr, 64, 2, 64, 3, 64, 1, 4};
        cp.d[2] = nul; cp.d[3] = nul;
        cp.rwd[0] = {op0_w, 192, 192, 6, 13392, 0};
        cp.rwd[1] = {op1_w, 192, 192, 6, 14040, 0};
        cp.rwd[2] = wnul; cp.rwd[3] = wnul;
        cp.rbeg[0] = 0; cp.rbeg[1] = 72; cp.rbeg[2] = 144; cp.rbeg[3] = 144; cp.rbeg[4] = 144;
        cp.nr = 2; cp.ride_bx0 = 8; cp.wgt = wgt;
        conv_mfma_k<4, 16><<<dim3(26, 8), 256, 0, stream>>>(cp);
    }
    // ---- 5. L4: so3 + aw3 ----
    {
        CParam cp;
        cp.d[0] = {s1, wgt + (size_t)2664 * 512, so3_b, so_t, nullptr, 64, 2, 1728, 1, 576,  0, 27};
        cp.d[1] = {a1, wgt + (size_t)4608 * 512, aw3_b, aw_t, nullptr, 64, 2, 7776, 2, 2592, 0, 122};
        cp.d[2] = nul; cp.d[3] = nul;
        cp.nr = 0; cp.ride_bx0 = BIG; cp.wgt = wgt;
        cp.rwd[0] = wnul; cp.rwd[1] = wnul; cp.rwd[2] = wnul; cp.rwd[3] = wnul;
        cp.rbeg[0] = 0; cp.rbeg[1] = 0; cp.rbeg[2] = 0; cp.rbeg[3] = 0; cp.rbeg[4] = 0;
        conv_mfma_k<8, 64><<<dim3(149, 4), 256, 0, stream>>>(cp);
    }

    // ---- 6. deformable attention ----
    deform_attn_k<<<768, 256, 0, stream>>>(value_b, so_t, aw_t,
                                           flow_1, flow_2, flip_1, flip_2,
                                           flow_cn2, flow_n2c, attn_pad);

    // ---- 7. op0 ----
    {
        CParam cp;
        cp.d[0] = {attn_pad, wgt + (size_t)13392 * 512, op0_b, op0h, nullptr, 192, 6, 192, 3, 192, 1, 12};
        cp.d[1] = nul; cp.d[2] = nul; cp.d[3] = nul;
        cp.nr = 0; cp.ride_bx0 = BIG; cp.wgt = wgt;
        cp.rwd[0] = wnul; cp.rwd[1] = wnul; cp.rwd[2] = wnul; cp.rwd[3] = wnul;
        cp.rbeg[0] = 0; cp.rbeg[1] = 0; cp.rbeg[2] = 0; cp.rbeg[3] = 0; cp.rbeg[4] = 0;
        conv_mfma_k<4, 16><<<dim3(12, 8), 256, 0, stream>>>(cp);
    }
    // ---- 8. op1 + residual ----
    {
        CParam cp;
        cp.d[0] = {op0h, wgt + (size_t)14040 * 512, op1_b, out, x, 192, 6, 192, 0, 0, 0, 12};
        cp.d[1] = nul; cp.d[2] = nul; cp.d[3] = nul;
        cp.nr = 0; cp.ride_bx0 = BIG; cp.wgt = wgt;
        cp.rwd[0] = wnul; cp.rwd[1] = wnul; cp.rwd[2] = wnul; cp.rwd[3] = wnul;
        cp.rbeg[0] = 0; cp.rbeg[1] = 0; cp.rbeg[2] = 0; cp.rbeg[3] = 0; cp.rbeg[4] = 0;
        conv_mfma_k<4, 16><<<dim3(12, 8), 256, 0, stream>>>(cp);
    }
}

// Round 12
// 266.467 us; speedup vs baseline: 3.0023x; 1.0580x over previous
//
#include <hip/hip_runtime.h>
#include <math.h>

#define HW 1024

typedef __attribute__((ext_vector_type(8))) short bf16x8;
typedef __attribute__((ext_vector_type(4))) float floatx4;

__device__ __forceinline__ unsigned short f2bf(float f) {
    unsigned u = __float_as_uint(f);
    u += 0x7FFF + ((u >> 16) & 1);
    return (unsigned short)(u >> 16);
}
__device__ __forceinline__ float bf2f(unsigned short u) {
    return __uint_as_float(((unsigned)u) << 16);
}
__device__ __forceinline__ float bflo(unsigned u) { return __uint_as_float(u << 16); }
__device__ __forceinline__ float bfhi(unsigned u) { return __uint_as_float(u & 0xffff0000u); }

// ---------------------------------------------------------------------------
// Bilinear sample, zero padding, absolute pixel coords (matches reference).
// ---------------------------------------------------------------------------
__device__ __forceinline__ float bilin32(const float* __restrict__ img, float px, float py) {
    float x0f = floorf(px), y0f = floorf(py);
    float wx = px - x0f, wy = py - y0f;
    bool vx0 = (x0f >= 0.f) && (x0f <= 31.f);
    bool vx1 = (x0f >= -1.f) && (x0f <= 30.f);
    bool vy0 = (y0f >= 0.f) && (y0f <= 31.f);
    bool vy1 = (y0f >= -1.f) && (y0f <= 30.f);
    int ix0 = (int)fminf(fmaxf(x0f, 0.f), 31.f);
    int iy0 = (int)fminf(fmaxf(y0f, 0.f), 31.f);
    int ix1 = (int)fminf(fmaxf(x0f + 1.f, 0.f), 31.f);
    int iy1 = (int)fminf(fmaxf(y0f + 1.f, 0.f), 31.f);
    float w00 = (1.f - wx) * (1.f - wy) * ((vx0 && vy0) ? 1.f : 0.f);
    float w01 = wx * (1.f - wy) * ((vx1 && vy0) ? 1.f : 0.f);
    float w10 = (1.f - wx) * wy * ((vx0 && vy1) ? 1.f : 0.f);
    float w11 = wx * wy * ((vx1 && vy1) ? 1.f : 0.f);
    return w00 * img[iy0 * 32 + ix0] + w01 * img[iy0 * 32 + ix1] +
           w10 * img[iy1 * 32 + ix0] + w11 * img[iy1 * 32 + ix1];
}

__device__ __forceinline__ float2 comp_flow(const float* __restrict__ fa,
                                            const float* __restrict__ fb, int pix) {
    int y = pix >> 5, x = pix & 31;
    float fx = fa[pix], fy = fa[HW + pix];
    float px = (float)x + fx, py = (float)y + fy;
    float2 r;
    r.x = fx + bilin32(fb, px, py);
    r.y = fy + bilin32(fb + HW, px, py);
    return r;
}

// ---------------------------------------------------------------------------
// Prep kernel: sections by blockIdx.x (grid 2336).
//  [0,192)     xpad: x -> x_pad bf16 [34*34][192]
//  [192,672)   build_extra, 4 channels/thread (shared bilinear coords)
//  [672,688)   flow_cn2 / flow_n2c fp32
//  [688,704)   border zeroing of the 9 padded bf16 buffers
//  [704,2336)  wxform: all 12 weight tensors -> bf16 MFMA fragment order
// ---------------------------------------------------------------------------
struct WD { const float* src; int cout, Cin, nCb, wbase, beg; };
struct PrepP {
    const float *x, *f1, *f2, *ff1, *ff2;
    float *fcn2, *fn2c;
    unsigned short *x_pad, *extra_pad, *wgt;
    WD wd[12];
};

__global__ __launch_bounds__(256) void prep_k(PrepP P) {
    __shared__ float wlds[16 * 288];
    const int b = blockIdx.x, tid = threadIdx.x;
    if (b < 192) {
        int idx = b * 256 + tid;                 // < 1024*48
        int pix = idx / 48, c4 = idx - pix * 48;
        int y = pix >> 5, xx = pix & 31;
        int c0 = c4 * 4;
        ushort4 s;
        s.x = f2bf(P.x[(size_t)(c0 + 0) * HW + pix]);
        s.y = f2bf(P.x[(size_t)(c0 + 1) * HW + pix]);
        s.z = f2bf(P.x[(size_t)(c0 + 2) * HW + pix]);
        s.w = f2bf(P.x[(size_t)(c0 + 3) * HW + pix]);
        *(ushort4*)(&P.x_pad[(size_t)((y + 1) * 34 + xx + 1) * 192 + c0]) = s;
    } else if (b < 672) {
        int idx = (b - 192) * 256 + tid;         // < 1024*120
        int pix = idx / 120, c4 = idx - pix * 120;
        int y = pix >> 5, xx = pix & 31;
        int c0 = c4 * 4;
        float va[4];
        if (c0 < 64) {
#pragma unroll
            for (int k = 0; k < 4; ++k) va[k] = P.x[(size_t)(c0 + k) * HW + pix];
        } else if (c0 < 448) {
            int grp = (c0 - 64) >> 6;
            int c = (c0 - 64) & 63;
            const float* src; float fx, fy;
            if (grp == 0)      { src = P.x + 64 * HW;  fx = P.f1[pix];  fy = P.f1[HW + pix]; }
            else if (grp == 1) { src = P.x + 128 * HW; float2 r = comp_flow(P.f1, P.f2, pix);  fx = r.x; fy = r.y; }
            else if (grp == 2) { src = P.x;            fx = P.ff1[pix]; fy = P.ff1[HW + pix]; }
            else if (grp == 3) { src = P.x + 128 * HW; fx = P.f2[pix];  fy = P.f2[HW + pix]; }
            else if (grp == 4) { src = P.x + 64 * HW;  fx = P.ff2[pix]; fy = P.ff2[HW + pix]; }
            else               { src = P.x;            float2 r = comp_flow(P.ff2, P.ff1, pix); fx = r.x; fy = r.y; }
            float px = (float)xx + fx, py = (float)y + fy;
            float x0f = floorf(px), y0f = floorf(py);
            float wx = px - x0f, wy = py - y0f;
            bool vx0 = (x0f >= 0.f) && (x0f <= 31.f);
            bool vx1 = (x0f >= -1.f) && (x0f <= 30.f);
            bool vy0 = (y0f >= 0.f) && (y0f <= 31.f);
            bool vy1 = (y0f >= -1.f) && (y0f <= 30.f);
            int ix0 = (int)fminf(fmaxf(x0f, 0.f), 31.f);
            int iy0 = (int)fminf(fmaxf(y0f, 0.f), 31.f);
            int ix1 = (int)fminf(fmaxf(x0f + 1.f, 0.f), 31.f);
            int iy1 = (int)fminf(fmaxf(y0f + 1.f, 0.f), 31.f);
            float w00 = (1.f - wx) * (1.f - wy) * ((vx0 && vy0) ? 1.f : 0.f);
            float w01 = wx * (1.f - wy) * ((vx1 && vy0) ? 1.f : 0.f);
            float w10 = (1.f - wx) * wy * ((vx0 && vy1) ? 1.f : 0.f);
            float w11 = wx * wy * ((vx1 && vy1) ? 1.f : 0.f);
            int p00 = iy0 * 32 + ix0, p01 = iy0 * 32 + ix1;
            int p10 = iy1 * 32 + ix0, p11 = iy1 * 32 + ix1;
            const float* im = src + (size_t)c * HW;
#pragma unroll
            for (int k = 0; k < 4; ++k) {
                va[k] = w00 * im[p00] + w01 * im[p01] + w10 * im[p10] + w11 * im[p11];
                im += HW;
            }
        } else {
#pragma unroll
            for (int k = 0; k < 4; ++k) {
                int ch = c0 + k;
                float v = 0.f;
                if (ch < 460) {
                    int fc = ch - 448;
                    int which = fc >> 1, comp = fc & 1;
                    if (which == 0)      v = P.f1[comp * HW + pix];
                    else if (which == 1) { float2 r = comp_flow(P.f1, P.f2, pix);  v = comp ? r.y : r.x; }
                    else if (which == 2) v = P.ff1[comp * HW + pix];
                    else if (which == 3) v = P.f2[comp * HW + pix];
                    else if (which == 4) v = P.ff2[comp * HW + pix];
                    else                 { float2 r = comp_flow(P.ff2, P.ff1, pix); v = comp ? r.y : r.x; }
                }
                va[k] = v;
            }
        }
        ushort4 s;
        s.x = f2bf(va[0]); s.y = f2bf(va[1]); s.z = f2bf(va[2]); s.w = f2bf(va[3]);
        *(ushort4*)(&P.extra_pad[(size_t)((y + 1) * 34 + xx + 1) * 480 + c0]) = s;
    } else if (b < 688) {
        int idx = (b - 672) * 256 + tid;
        if (idx < 1024) {
            float2 r = comp_flow(P.f1, P.f2, idx);
            P.fcn2[idx] = r.x; P.fcn2[HW + idx] = r.y;
        } else if (idx < 2048) {
            int pix = idx - 1024;
            float2 r = comp_flow(P.ff2, P.ff1, pix);
            P.fn2c[pix] = r.x; P.fn2c[HW + pix] = r.y;
        }
    } else if (b < 704) {
        const int chans[9] = {192, 192, 480, 64, 64, 64, 64, 192, 192};
        size_t offs[9]; size_t a = 0;
        for (int i = 0; i < 9; ++i) { offs[i] = a; a += (size_t)1156 * chans[i]; }
        int bb = b - 688;
        for (int item = bb; item < 9 * 132; item += 16) {
            int buf = item / 132, i = item - buf * 132;
            int py, px;
            if (i < 34) { py = 0; px = i; }
            else if (i < 68) { py = 33; px = i - 34; }
            else { int j = i - 68; py = 1 + (j >> 1); px = (j & 1) ? 33 : 0; }
            int C = chans[buf];
            unsigned short* p = P.x_pad + offs[buf] + (size_t)(py * 34 + px) * C;
            for (int c = tid; c < C; c += 256) p[c] = 0;
        }
    } else {
        int blk = b - 704;                       // < 1632
        int di = 0;
        while (di < 11 && blk >= P.wd[di + 1].beg) ++di;
        WD w = P.wd[di];
        int local = blk - w.beg;
        int co16 = local / w.nCb, cb = local - co16 * w.nCb;
        int cr0 = co16 * 16, ci0 = cb * 32;
        for (int i = tid; i < 16 * 288; i += 256) {
            int cr = i / 288, o = i - cr * 288;
            int crg = cr0 + cr, ci = ci0 + o / 9;
            float v = (crg < w.cout && ci < w.Cin)
                ? w.src[((size_t)crg * w.Cin + ci0) * 9 + o] : 0.f;
            wlds[i] = v;
        }
        __syncthreads();
        for (int e = tid; e < 9 * 512; e += 256) {
            int t = e >> 9, idx = e & 511;
            int j = idx & 7, lane = idx >> 3, q = lane >> 4, mm = lane & 15;
            P.wgt[((size_t)w.wbase + ((size_t)co16 * 9 + t) * w.nCb + cb) * 512 + idx] =
                f2bf(wlds[mm * 288 + (q * 8 + j) * 9 + t]);
        }
    }
}

// ---------------------------------------------------------------------------
// MFMA 3x3 conv, multi-descriptor, register-prefetch double-buffered.
// ---------------------------------------------------------------------------
struct CDesc {
    const unsigned short* in;
    const unsigned short* wgt;
    const float* bias;
    void* out;
    const float* residual;
    int Cpad, nCb, Cout, mode, cmod, relu, Mblocks;
};
struct CParam { CDesc d[4]; };

template<int PIXROWS, int COBLK>
__global__ __launch_bounds__(256) void conv_mfma_k(CParam P) {
    constexpr int TROWS = PIXROWS + 2;
    constexpr int TC = TROWS * 34 * 4;
    constexpr int ITRIPS = (TC + 255) / 256;
    constexpr int NTY = PIXROWS / 4;
    constexpr int NACC = NTY * 2;
    constexpr int MT = COBLK / 16;
    constexpr int WN = MT * 9 * 64;
    constexpr int WTRIPS = (WN + 255) / 256;
    __shared__ unsigned short blds[TROWS * 34 * 40];
    __shared__ unsigned short wlds[MT * 9 * 512];

    int bx = blockIdx.x;
    int di = 0;
    while (bx >= P.d[di].Mblocks) { bx -= P.d[di].Mblocks; ++di; }
    const CDesc d = P.d[di];

    const int tid = threadIdx.x;
    const int w = tid >> 6, lane = tid & 63;
    const int lq = lane >> 4, ln = lane & 15;
    const int co0 = bx * COBLK;
    const int by = blockIdx.y, y0 = by * PIXROWS;
    const unsigned short* __restrict__ in = d.in;
    const unsigned short* __restrict__ wg = d.wgt;
    const int Cpad = d.Cpad, nCb = d.nCb;

    floatx4 acc[MT][NACC];
#pragma unroll
    for (int mt = 0; mt < MT; ++mt)
#pragma unroll
        for (int nt = 0; nt < NACC; ++nt)
            acc[mt][nt] = (floatx4){0.f, 0.f, 0.f, 0.f};

    bf16x8 ireg[ITRIPS];
    bf16x8 wreg[WTRIPS];

    auto load_regs = [&](int cb) {
        const int ci0 = cb << 5;
#pragma unroll
        for (int k = 0; k < ITRIPS; ++k) {
            int i = tid + k * 256;
            if (i < TC) {
                int r = i / 136, rem = i - r * 136, c = rem >> 2, g = rem & 3;
                ireg[k] = *(const bf16x8*)(in + (size_t)((y0 + r) * 34 + c) * Cpad + ci0 + g * 8);
            }
        }
#pragma unroll
        for (int k = 0; k < WTRIPS; ++k) {
            int i = tid + k * 256;
            if (i < WN) {
                int chunk = i >> 6, l16 = i & 63;
                int mt = chunk / 9, t = chunk - mt * 9;
                wreg[k] = *(const bf16x8*)(wg + ((size_t)(((co0 >> 4) + mt) * 9 + t) * nCb + cb) * 512 + l16 * 8);
            }
        }
    };

    load_regs(0);

    for (int cb = 0; cb < nCb; ++cb) {
        __syncthreads();
#pragma unroll
        for (int k = 0; k < ITRIPS; ++k) {
            int i = tid + k * 256;
            if (i < TC) {
                int r = i / 136, rem = i - r * 136, c = rem >> 2, g = rem & 3;
                *(bf16x8*)(&blds[(r * 34 + c) * 40 + g * 8]) = ireg[k];
            }
        }
#pragma unroll
        for (int k = 0; k < WTRIPS; ++k) {
            int i = tid + k * 256;
            if (i < WN) {
                int chunk = i >> 6, l16 = i & 63;
                *(bf16x8*)(&wlds[chunk * 512 + l16 * 8]) = wreg[k];
            }
        }
        __syncthreads();
        if (cb + 1 < nCb) load_regs(cb + 1);
        for (int t = 0; t < 9; ++t) {
            const int dy = t / 3, dx = t - dy * 3;
            bf16x8 bfr[NACC];
#pragma unroll
            for (int ty = 0; ty < NTY; ++ty)
#pragma unroll
                for (int tx = 0; tx < 2; ++tx) {
                    int yy = w * NTY + ty + dy;
                    int xx = tx * 16 + ln + dx;
                    bfr[ty * 2 + tx] = *(const bf16x8*)(&blds[(yy * 34 + xx) * 40 + lq * 8]);
                }
#pragma unroll
            for (int mt = 0; mt < MT; ++mt) {
                bf16x8 afr = *(const bf16x8*)(&wlds[(mt * 9 + t) * 512 + lane * 8]);
#pragma unroll
                for (int nt = 0; nt < NACC; ++nt)
                    acc[mt][nt] = __builtin_amdgcn_mfma_f32_16x16x32_bf16(afr, bfr[nt], acc[mt][nt], 0, 0, 0);
            }
        }
    }

#pragma unroll
    for (int mt = 0; mt < MT; ++mt) {
        const int co = co0 + mt * 16 + lq * 4;
        if (co >= d.Cout) continue;
        float bv[4];
#pragma unroll
        for (int r = 0; r < 4; ++r) bv[r] = d.bias[co + r];
#pragma unroll
        for (int nt = 0; nt < NACC; ++nt) {
            const int ty = nt >> 1, tx = nt & 1;
            const int pix = by * (PIXROWS * 32) + (w * NTY + ty) * 32 + tx * 16 + ln;
            float v[4];
#pragma unroll
            for (int r = 0; r < 4; ++r) {
                float vv = acc[mt][nt][r] + bv[r];
                if (d.relu) vv = (vv >= 0.f) ? vv : 0.1f * vv;
                v[r] = vv;
            }
            if (d.mode == 0) {
                float* o = (float*)d.out;
#pragma unroll
                for (int r = 0; r < 4; ++r) {
                    float vv = v[r];
                    if (d.residual) vv += d.residual[(size_t)(co + r) * HW + pix];
                    o[(size_t)(co + r) * HW + pix] = vv;
                }
            } else if (d.mode == 1) {
                int fq = co / d.cmod, cc = co - fq * d.cmod;
                *(float4*)((float*)d.out + ((size_t)fq * HW + pix) * d.cmod + cc) =
                    make_float4(v[0], v[1], v[2], v[3]);
            } else if (d.mode == 2) {
                int fq = co / d.cmod, cc = co - fq * d.cmod;
                ushort4 s4;
                s4.x = f2bf(v[0]); s4.y = f2bf(v[1]); s4.z = f2bf(v[2]); s4.w = f2bf(v[3]);
                *(ushort4*)((unsigned short*)d.out + ((size_t)fq * HW + pix) * d.cmod + cc) = s4;
            } else {
                int yy = (pix >> 5) + 1, xx = (pix & 31) + 1;
                ushort4 s4;
                s4.x = f2bf(v[0]); s4.y = f2bf(v[1]); s4.z = f2bf(v[2]); s4.w = f2bf(v[3]);
                *(ushort4*)((unsigned short*)d.out + (size_t)(yy * 34 + xx) * d.cmod + co) = s4;
            }
        }
    }
}

// ---------------------------------------------------------------------------
// Deformable attention: LDS value + patch-convolution gathers + software
// pipelining (so-offset loads hoisted; next q's logits prefetched).
// ---------------------------------------------------------------------------
__global__ __launch_bounds__(256) void deform_attn_k(
    const unsigned short* __restrict__ value_b, const float* __restrict__ so_t,
    const unsigned short* __restrict__ aw_t,
    const float* __restrict__ flow_1, const float* __restrict__ flow_2,
    const float* __restrict__ flip_flow_1, const float* __restrict__ flip_flow_2,
    const float* __restrict__ flow_cn2, const float* __restrict__ flow_n2c,
    unsigned short* __restrict__ attn_pad)
{
    __shared__ unsigned short vlds[24576];
    __shared__ unsigned short pwlds[4][432];
    const int tid = threadIdx.x;
    const int wav = tid >> 6, lane = tid & 63;
    const int m = blockIdx.x & 7, qc = blockIdx.x >> 3;

    for (int i = tid; i < 3072; i += 256) {
        int l = i >> 10, p = i & 1023;
        *(bf16x8*)(&vlds[(size_t)i * 8]) =
            *(const bf16x8*)(value_b + ((size_t)((l * 8 + m) * 1024) + p) * 8);
    }
    __syncthreads();

    const int pp = lane & 15, gq = lane >> 4;
    const int gdy = (gq >> 1) * 2 - 1;
    const int gdx = (gq & 1) * 2 - 1;
    const bool selx = (gq & 1);
    const bool sely = (gq >> 1);

    float av[6];
    {
        const unsigned short* awp = aw_t + (size_t)(qc * 32 + wav) * 2592 + m * 324;
#pragma unroll
        for (int it = 0; it < 6; ++it) {
            int j = lane + it * 64;
            av[it] = (j < 324) ? bf2f(awp[j]) : -1e30f;
        }
    }

    for (int r = 0; r < 8; ++r) {
        const int q = qc * 32 + r * 4 + wav;
        const int f = q >> 10, pix = q & 1023;
        const int y = pix >> 5, x = pix & 31;

        const float* sop = so_t + (size_t)q * 576 + m * 72;
        float2 so2r[3];
#pragma unroll
        for (int pt = 0; pt < 3; ++pt) {
            int pi = pt * 16 + pp;
            if (pi < 36) so2r[pt] = *(const float2*)(sop + pi * 2);
            else { so2r[pt].x = 0.f; so2r[pt].y = 0.f; }
        }

        float flx0 = 0.f, fly0 = 0.f, flx1 = 0.f, fly1 = 0.f, flx2 = 0.f, fly2 = 0.f;
        if (f == 0) {
            flx1 = flow_1[pix];      fly1 = flow_1[HW + pix];
            flx2 = flow_cn2[pix];    fly2 = flow_cn2[HW + pix];
        } else if (f == 1) {
            flx0 = flip_flow_1[pix]; fly0 = flip_flow_1[HW + pix];
            flx2 = flow_2[pix];      fly2 = flow_2[HW + pix];
        } else {
            flx0 = flow_n2c[pix];    fly0 = flow_n2c[HW + pix];
            flx1 = flip_flow_2[pix]; fly1 = flip_flow_2[HW + pix];
        }

        float vmax = -1e30f;
#pragma unroll
        for (int it = 0; it < 6; ++it) vmax = fmaxf(vmax, av[it]);
#pragma unroll
        for (int off = 32; off; off >>= 1) vmax = fmaxf(vmax, __shfl_xor(vmax, off));
        float ssum = 0.f;
#pragma unroll
        for (int it = 0; it < 6; ++it) {
            int j = lane + it * 64;
            float e = (j < 324) ? __expf(av[it] - vmax) : 0.f;
            av[it] = e;
            ssum += e;
        }
#pragma unroll
        for (int off = 32; off; off >>= 1) ssum += __shfl_xor(ssum, off);
        const float inv = 1.f / ssum;

#pragma unroll
        for (int it = 0; it < 6; ++it) {
            int j = lane + it * 64;
            if (j < 324) {
                int pi = j / 9, k = j - pi * 9;
                pwlds[wav][pi * 12 + k] = f2bf(av[it] * inv);
            }
        }

        float avn[6];
        if (r < 7) {
            const unsigned short* awn = aw_t + (size_t)(q + 4) * 2592 + m * 324;
#pragma unroll
            for (int it = 0; it < 6; ++it) {
                int j = lane + it * 64;
                avn[it] = (j < 324) ? bf2f(awn[j]) : -1e30f;
            }
        }

        float acc[8];
#pragma unroll
        for (int dd = 0; dd < 8; ++dd) acc[dd] = 0.f;

#pragma unroll
        for (int pt = 0; pt < 3; ++pt) {
            int pi = pt * 16 + pp;
            if (pi < 36) {
                int l = pi / 12;
                float2 so2 = so2r[pt];
                float fx = (l == 0) ? flx0 : (l == 1) ? flx1 : flx2;
                float fy = (l == 0) ? fly0 : (l == 1) ? fly1 : fly2;
                float bxf = (float)x + so2.x + fx;
                float byf = (float)y + so2.y + fy;
                float x0f = floorf(bxf), y0f = floorf(byf);
                float wx = bxf - x0f, wy = byf - y0f;
                float ax = 1.f - wx, ay = 1.f - wy;
                int x0 = (int)fminf(fmaxf(x0f, -2.f), 34.f);
                int y0 = (int)fminf(fmaxf(y0f, -2.f), 34.f);

                const unsigned short* pr = &pwlds[wav][pi * 12];
                uint2 pv0 = *(const uint2*)(pr);
                uint2 pv1 = *(const uint2*)(pr + 4);
                float a0 = bflo(pv0.x), a1 = bfhi(pv0.x), a2 = bflo(pv0.y);
                float a3 = bfhi(pv0.y), a4 = bflo(pv1.x), a5 = bfhi(pv1.x);
                float a6 = bflo(pv1.y), a7 = bfhi(pv1.y), a8 = bf2f(pr[8]);

                float bs0a, bs0b, bs1a, bs1b, bs2a, bs2b;
                {
                    float b0, b1, b2, b3;
                    b0 = a0 * ax; b1 = a0 * wx + a3 * ax; b2 = a3 * wx + a6 * ax; b3 = a6 * wx;
                    bs0a = selx ? b2 : b0; bs0b = selx ? b3 : b1;
                    b0 = a1 * ax; b1 = a1 * wx + a4 * ax; b2 = a4 * wx + a7 * ax; b3 = a7 * wx;
                    bs1a = selx ? b2 : b0; bs1b = selx ? b3 : b1;
                    b0 = a2 * ax; b1 = a2 * wx + a5 * ax; b2 = a5 * wx + a8 * ax; b3 = a8 * wx;
                    bs2a = selx ? b2 : b0; bs2b = selx ? b3 : b1;
                }
                float c00, c01, c10, c11;
                {
                    float c0 = bs0a * ay, c1 = bs0a * wy + bs1a * ay;
                    float c2 = bs1a * wy + bs2a * ay, c3 = bs2a * wy;
                    c00 = sely ? c2 : c0; c10 = sely ? c3 : c1;
                    c0 = bs0b * ay; c1 = bs0b * wy + bs1b * ay;
                    c2 = bs1b * wy + bs2b * ay; c3 = bs2b * wy;
                    c01 = sely ? c2 : c0; c11 = sely ? c3 : c1;
                }
                float cg[2][2] = {{c00, c01}, {c10, c11}};
                const int vbase = l * 1024;
#pragma unroll
                for (int sy = 0; sy < 2; ++sy) {
#pragma unroll
                    for (int sx = 0; sx < 2; ++sx) {
                        int dy = gdy + sy, dx = gdx + sx;
                        float pyf = y0f + (float)dy, pxf = x0f + (float)dx;
                        bool v = (pxf >= 0.f) && (pxf <= 31.f) && (pyf >= 0.f) && (pyf <= 31.f);
                        int px = min(max(x0 + dx, 0), 31);
                        int py = min(max(y0 + dy, 0), 31);
                        float c = cg[sy][sx] * (v ? 1.f : 0.f);
                        uint4 vv = *(const uint4*)(&vlds[(size_t)(vbase + py * 32 + px) * 8]);
                        acc[0] = fmaf(c, bflo(vv.x), acc[0]);
                        acc[1] = fmaf(c, bfhi(vv.x), acc[1]);
                        acc[2] = fmaf(c, bflo(vv.y), acc[2]);
                        acc[3] = fmaf(c, bfhi(vv.y), acc[3]);
                        acc[4] = fmaf(c, bflo(vv.z), acc[4]);
                        acc[5] = fmaf(c, bfhi(vv.z), acc[5]);
                        acc[6] = fmaf(c, bflo(vv.w), acc[6]);
                        acc[7] = fmaf(c, bfhi(vv.w), acc[7]);
                    }
                }
            }
        }

#pragma unroll
        for (int dd = 0; dd < 8; ++dd) {
#pragma unroll
            for (int off = 32; off; off >>= 1) acc[dd] += __shfl_xor(acc[dd], off);
        }
        if (lane == 0) {
            unsigned short* op = attn_pad + (size_t)((y + 1) * 34 + x + 1) * 192 + f * 64 + m * 8;
            ushort4 s0, s1;
            s0.x = f2bf(acc[0]); s0.y = f2bf(acc[1]); s0.z = f2bf(acc[2]); s0.w = f2bf(acc[3]);
            s1.x = f2bf(acc[4]); s1.y = f2bf(acc[5]); s1.z = f2bf(acc[6]); s1.w = f2bf(acc[7]);
            *(ushort4*)(op) = s0;
            *(ushort4*)(op + 4) = s1;
        }
        if (r < 7) {
#pragma unroll
            for (int it = 0; it < 6; ++it) av[it] = avn[it];
        }
    }
}

// ---------------------------------------------------------------------------
extern "C" void kernel_launch(void* const* d_in, const int* in_sizes, int n_in,
                              void* d_out, int out_size, void* d_ws, size_t ws_size,
                              hipStream_t stream) {
    const float* x      = (const float*)d_in[0];
    const float* flow_1 = (const float*)d_in[1];
    const float* flow_2 = (const float*)d_in[2];
    const float* flip_1 = (const float*)d_in[3];
    const float* flip_2 = (const float*)d_in[4];
    const float* vp0_w = (const float*)d_in[5];  const float* vp0_b = (const float*)d_in[6];
    const float* vp1_w = (const float*)d_in[7];  const float* vp1_b = (const float*)d_in[8];
    const float* so0_w = (const float*)d_in[9];  const float* so0_b = (const float*)d_in[10];
    const float* so1_w = (const float*)d_in[11]; const float* so1_b = (const float*)d_in[12];
    const float* so2_w = (const float*)d_in[13]; const float* so2_b = (const float*)d_in[14];
    const float* so3_w = (const float*)d_in[15]; const float* so3_b = (const float*)d_in[16];
    const float* aw0_w = (const float*)d_in[17]; const float* aw0_b = (const float*)d_in[18];
    const float* aw1_w = (const float*)d_in[19]; const float* aw1_b = (const float*)d_in[20];
    const float* aw2_w = (const float*)d_in[21]; const float* aw2_b = (const float*)d_in[22];
    const float* aw3_w = (const float*)d_in[23]; const float* aw3_b = (const float*)d_in[24];
    const float* op0_w = (const float*)d_in[25]; const float* op0_b = (const float*)d_in[26];
    const float* op1_w = (const float*)d_in[27]; const float* op1_b = (const float*)d_in[28];
    float* out = (float*)d_out;
    (void)ws_size; (void)in_sizes; (void)n_in; (void)out_size;

    // ---- workspace layout (round-8) ----
    float* fws = (float*)d_ws;
    float* flow_cn2 = fws;
    float* flow_n2c = flow_cn2 + 2048;
    unsigned short* value_b = (unsigned short*)(flow_n2c + 2048);
    float* so_t     = (float*)(value_b + 196608);
    unsigned short* uws = (unsigned short*)(so_t + 1769472);
    unsigned short* x_pad     = uws;
    unsigned short* vp0h      = x_pad + 1156 * 192;
    unsigned short* extra_pad = vp0h + 1156 * 192;
    unsigned short* s1 = extra_pad + 1156 * 480;
    unsigned short* a1 = s1 + 1156 * 64;
    unsigned short* s2 = a1 + 1156 * 64;
    unsigned short* a2 = s2 + 1156 * 64;
    unsigned short* attn_pad = a2 + 1156 * 64;
    unsigned short* op0h     = attn_pad + 1156 * 192;
    unsigned short* aw_t = op0h + 1156 * 192;
    unsigned short* wgt  = aw_t + (size_t)3072 * 2592;

    // ---- 1. prep (all wxform back in prep; build_extra vectorized) ----
    PrepP pp;
    pp.x = x; pp.f1 = flow_1; pp.f2 = flow_2; pp.ff1 = flip_1; pp.ff2 = flip_2;
    pp.fcn2 = flow_cn2; pp.fn2c = flow_n2c;
    pp.x_pad = x_pad; pp.extra_pad = extra_pad; pp.wgt = wgt;
    pp.wd[0]  = {vp0_w, 192, 192, 6,     0,    0};
    pp.wd[1]  = {vp1_w, 192, 192, 6,   648,   72};
    pp.wd[2]  = {so0_w,  64, 460, 15, 1296,  144};
    pp.wd[3]  = {aw0_w,  64, 460, 15, 1836,  204};
    pp.wd[4]  = {so1_w,  64,  64, 2,  2376,  264};
    pp.wd[5]  = {aw1_w,  64,  64, 2,  2448,  272};
    pp.wd[6]  = {so2_w,  64,  64, 2,  2520,  280};
    pp.wd[7]  = {aw2_w,  64,  64, 2,  2592,  288};
    pp.wd[8]  = {so3_w, 1728, 64, 2,  2664,  296};
    pp.wd[9]  = {aw3_w, 7776, 64, 2,  4608,  512};
    pp.wd[10] = {op0_w, 192, 192, 6, 13392, 1488};
    pp.wd[11] = {op1_w, 192, 192, 6, 14040, 1560};
    prep_k<<<2336, 256, 0, stream>>>(pp);

    const int BIG = 1 << 30;
    CDesc nul = {nullptr, nullptr, nullptr, nullptr, nullptr, 0, 0, 0, 0, 0, 0, BIG};

    // ---- 2. L1: vp0 + so0 + aw0 ----
    {
        CParam cp;
        cp.d[0] = {x_pad,     wgt + (size_t)0 * 512,    vp0_b, vp0h, nullptr, 192, 6,  192, 3, 192, 1, 12};
        cp.d[1] = {extra_pad, wgt + (size_t)1296 * 512, so0_b, s1,   nullptr, 480, 15, 64,  3, 64,  1, 4};
        cp.d[2] = {extra_pad, wgt + (size_t)1836 * 512, aw0_b, a1,   nullptr, 480, 15, 64,  3, 64,  1, 4};
        cp.d[3] = nul;
        conv_mfma_k<4, 16><<<dim3(20, 8), 256, 0, stream>>>(cp);
    }
    // ---- 3. L2: vp1 + so1 + aw1 ----
    {
        CParam cp;
        cp.d[0] = {vp0h, wgt + (size_t)648 * 512,  vp1_b, value_b, nullptr, 192, 6, 192, 2, 8,  0, 12};
        cp.d[1] = {s1,   wgt + (size_t)2376 * 512, so1_b, s2,      nullptr, 64,  2, 64,  3, 64, 1, 4};
        cp.d[2] = {a1,   wgt + (size_t)2448 * 512, aw1_b, a2,      nullptr, 64,  2, 64,  3, 64, 1, 4};
        cp.d[3] = nul;
        conv_mfma_k<4, 16><<<dim3(20, 8), 256, 0, stream>>>(cp);
    }
    // ---- 4. L3: so2 + aw2 ----
    {
        CParam cp;
        cp.d[0] = {s2, wgt + (size_t)2520 * 512, so2_b, s1, nullptr, 64, 2, 64, 3, 64, 1, 4};
        cp.d[1] = {a2, wgt + (size_t)2592 * 512, aw2_b, a1, nullptr, 64, 2, 64, 3, 64, 1, 4};
        cp.d[2] = nul; cp.d[3] = nul;
        conv_mfma_k<4, 16><<<dim3(8, 8), 256, 0, stream>>>(cp);
    }
    // ---- 5. L4: so3 + aw3 ----
    {
        CParam cp;
        cp.d[0] = {s1, wgt + (size_t)2664 * 512, so3_b, so_t, nullptr, 64, 2, 1728, 1, 576,  0, 27};
        cp.d[1] = {a1, wgt + (size_t)4608 * 512, aw3_b, aw_t, nullptr, 64, 2, 7776, 2, 2592, 0, 122};
        cp.d[2] = nul; cp.d[3] = nul;
        conv_mfma_k<8, 64><<<dim3(149, 4), 256, 0, stream>>>(cp);
    }

    // ---- 6. deformable attention ----
    deform_attn_k<<<768, 256, 0, stream>>>(value_b, so_t, aw_t,
                                           flow_1, flow_2, flip_1, flip_2,
                                           flow_cn2, flow_n2c, attn_pad);

    // ---- 7. op0 ----
    {
        CParam cp;
        cp.d[0] = {attn_pad, wgt + (size_t)13392 * 512, op0_b, op0h, nullptr, 192, 6, 192, 3, 192, 1, 12};
        cp.d[1] = nul; cp.d[2] = nul; cp.d[3] = nul;
        conv_mfma_k<4, 16><<<dim3(12, 8), 256, 0, stream>>>(cp);
    }
    // ---- 8. op1 + residual ----
    {
        CParam cp;
        cp.d[0] = {op0h, wgt + (size_t)14040 * 512, op1_b, out, x, 192, 6, 192, 0, 0, 0, 12};
        cp.d[1] = nul; cp.d[2] = nul; cp.d[3] = nul;
        conv_mfma_k<4, 16><<<dim3(12, 8), 256, 0, stream>>>(cp);
    }
}